// Round 1
// baseline (3625.124 us; speedup 1.0000x reference)
//
#include <hip/hip_runtime.h>
#include <math.h>

#define D4   4
#define NB   64      // batch = #filters = #observations
#define T    2048
#define TP1  2049
#define HID  20
#define POS  3
#define CH   64      // chunks for backward parallel scan
#define CLEN 32      // chunk length (CH*CLEN >= T-1)

#define LOG_2PI 1.8378770664093453f

// ---- workspace layout (floats) -------------------------------------------
// xhat  : TP1*NB*4      = 524544
// sigma : TP1*NB*4      = 524544
// fm    : T*NB*4        = 524288
// fP    : T*NB*16       = 2097152
// C     : NB*CH*36      = 147456
// E     : NB*CH*36      = 147456
// total = 3965440 floats = 15.9 MB
#define OFF_XHAT  0
#define OFF_SIGMA (TP1*NB*4)
#define OFF_FM    (2*TP1*NB*4)
#define OFF_FP    (OFF_FM + T*NB*4)
#define OFF_C     (OFF_FP + T*NB*16)
#define OFF_E     (OFF_C + NB*CH*36)

// ---- wave helpers ---------------------------------------------------------
__device__ __forceinline__ float wave_sum(float v) {
  v += __shfl_xor(v, 1);
  v += __shfl_xor(v, 2);
  v += __shfl_xor(v, 4);
  v += __shfl_xor(v, 8);
  v += __shfl_xor(v, 16);
  v += __shfl_xor(v, 32);
  return v;
}
__device__ __forceinline__ float wave_max(float v) {
  v = fmaxf(v, __shfl_xor(v, 1));
  v = fmaxf(v, __shfl_xor(v, 2));
  v = fmaxf(v, __shfl_xor(v, 4));
  v = fmaxf(v, __shfl_xor(v, 8));
  v = fmaxf(v, __shfl_xor(v, 16));
  v = fmaxf(v, __shfl_xor(v, 32));
  return v;
}

// ---- 4x4 inverse (adjugate); returns det ---------------------------------
__device__ __forceinline__ float inv4(const float a[4][4], float inv[4][4]) {
  float s0 = a[0][0]*a[1][1] - a[1][0]*a[0][1];
  float s1 = a[0][0]*a[1][2] - a[1][0]*a[0][2];
  float s2 = a[0][0]*a[1][3] - a[1][0]*a[0][3];
  float s3 = a[0][1]*a[1][2] - a[1][1]*a[0][2];
  float s4 = a[0][1]*a[1][3] - a[1][1]*a[0][3];
  float s5 = a[0][2]*a[1][3] - a[1][2]*a[0][3];
  float c5 = a[2][2]*a[3][3] - a[3][2]*a[2][3];
  float c4 = a[2][1]*a[3][3] - a[3][1]*a[2][3];
  float c3 = a[2][1]*a[3][2] - a[3][1]*a[2][2];
  float c2 = a[2][0]*a[3][3] - a[3][0]*a[2][3];
  float c1 = a[2][0]*a[3][2] - a[3][0]*a[2][2];
  float c0 = a[2][0]*a[3][1] - a[3][0]*a[2][1];
  float det = s0*c5 - s1*c4 + s2*c3 + s3*c2 - s4*c1 + s5*c0;
  float id = __fdividef(1.0f, det);
  inv[0][0] = ( a[1][1]*c5 - a[1][2]*c4 + a[1][3]*c3) * id;
  inv[0][1] = (-a[0][1]*c5 + a[0][2]*c4 - a[0][3]*c3) * id;
  inv[0][2] = ( a[3][1]*s5 - a[3][2]*s4 + a[3][3]*s3) * id;
  inv[0][3] = (-a[2][1]*s5 + a[2][2]*s4 - a[2][3]*s3) * id;
  inv[1][0] = (-a[1][0]*c5 + a[1][2]*c2 - a[1][3]*c1) * id;
  inv[1][1] = ( a[0][0]*c5 - a[0][2]*c2 + a[0][3]*c1) * id;
  inv[1][2] = (-a[3][0]*s5 + a[3][2]*s2 - a[3][3]*s1) * id;
  inv[1][3] = ( a[2][0]*s5 - a[2][2]*s2 + a[2][3]*s1) * id;
  inv[2][0] = ( a[1][0]*c4 - a[1][1]*c2 + a[1][3]*c0) * id;
  inv[2][1] = (-a[0][0]*c4 + a[0][1]*c2 - a[0][3]*c0) * id;
  inv[2][2] = ( a[3][0]*s4 - a[3][1]*s2 + a[3][3]*s0) * id;
  inv[2][3] = (-a[2][0]*s4 + a[2][1]*s2 - a[2][3]*s0) * id;
  inv[3][0] = (-a[1][0]*c3 + a[1][1]*c1 - a[1][2]*c0) * id;
  inv[3][1] = ( a[0][0]*c3 - a[0][1]*c1 + a[0][2]*c0) * id;
  inv[3][2] = (-a[3][0]*s3 + a[3][1]*s1 - a[3][2]*s0) * id;
  inv[3][3] = ( a[2][0]*s3 - a[2][1]*s1 + a[2][2]*s0) * id;
  return det;
}

// ---- Q = L L^T from q_param (tril_indices row-major order) ---------------
__device__ __forceinline__ void build_Q(const float* __restrict__ qp, float Q[4][4]) {
  float L[4][4] = {{0.f,0.f,0.f,0.f},{0.f,0.f,0.f,0.f},{0.f,0.f,0.f,0.f},{0.f,0.f,0.f,0.f}};
  L[0][0] = expf(qp[0]);
  L[1][0] = qp[1]; L[1][1] = expf(qp[2]);
  L[2][0] = qp[3]; L[2][1] = qp[4]; L[2][2] = expf(qp[5]);
  L[3][0] = qp[6]; L[3][1] = qp[7]; L[3][2] = qp[8]; L[3][3] = expf(qp[9]);
#pragma unroll
  for (int r = 0; r < 4; ++r)
#pragma unroll
    for (int c = 0; c < 4; ++c) {
      float v = 0.f;
#pragma unroll
      for (int k = 0; k < 4; ++k) v += L[r][k] * L[c][k];
      Q[r][c] = v;
    }
}

__device__ __forceinline__ void load_A_b_Q(const float* __restrict__ Ag,
                                           const float* __restrict__ bg,
                                           const float* __restrict__ qp,
                                           float A[4][4], float b[4], float Q[4][4]) {
#pragma unroll
  for (int r = 0; r < 4; ++r) {
    b[r] = bg[r];
#pragma unroll
    for (int c = 0; c < 4; ++c) A[r][c] = Ag[r * 4 + c];
  }
  build_Q(qp, Q);
}

// ==========================================================================
// K1: encoder — xhat, sigma for all (t,n)
// ==========================================================================
__global__ void k_encoder(const float* __restrict__ x,
                          const float* __restrict__ w1, const float* __restrict__ b1,
                          const float* __restrict__ wx, const float* __restrict__ bx,
                          const float* __restrict__ wl, const float* __restrict__ bl,
                          float* __restrict__ xhat, float* __restrict__ sigma) {
  int idx = blockIdx.x * blockDim.x + threadIdx.x;
  if (idx >= TP1 * NB) return;
  float x0 = x[idx*3+0], x1 = x[idx*3+1], x2 = x[idx*3+2];
  float xh[4], lm[4];
#pragma unroll
  for (int k = 0; k < 4; ++k) { xh[k] = bx[k]; lm[k] = bl[k]; }
#pragma unroll
  for (int j = 0; j < HID; ++j) {
    float h = x0*w1[0*HID+j] + x1*w1[1*HID+j] + x2*w1[2*HID+j] + b1[j];
    h = fmaxf(h, 0.0f);
#pragma unroll
    for (int k = 0; k < 4; ++k) { xh[k] += h * wx[j*4+k]; lm[k] += h * wl[j*4+k]; }
  }
  *(float4*)&xhat[(size_t)idx*4]  = make_float4(xh[0], xh[1], xh[2], xh[3]);
  *(float4*)&sigma[(size_t)idx*4] = make_float4(expf(0.5f*lm[0]), expf(0.5f*lm[1]),
                                                expf(0.5f*lm[2]), expf(0.5f*lm[3]));
}

// ==========================================================================
// K2: forward mixture Kalman filter — one wave per filter, lane = observation
// ==========================================================================
__global__ void __launch_bounds__(64, 1) k_filter(
    const float* __restrict__ xhat, const float* __restrict__ sigma,
    const float* __restrict__ Ag, const float* __restrict__ bg,
    const float* __restrict__ qp,
    float* __restrict__ fm, float* __restrict__ fP) {
  const int i = blockIdx.x;   // filter
  const int n = threadIdx.x;  // observation lane

  float A[4][4], Q[4][4], b[4];
  load_A_b_Q(Ag, bg, qp, A, b, Q);

  float m[4], P[4][4];
  {
    float4 m0 = *(const float4*)&xhat[i*4];
    float4 s0 = *(const float4*)&sigma[i*4];
    m[0]=m0.x; m[1]=m0.y; m[2]=m0.z; m[3]=m0.w;
#pragma unroll
    for (int r = 0; r < 4; ++r)
#pragma unroll
      for (int c = 0; c < 4; ++c) P[r][c] = 0.0f;
    P[0][0]=s0.x; P[1][1]=s0.y; P[2][2]=s0.z; P[3][3]=s0.w;
  }

  // preload obs row 1 (step t uses row t+1)
  float4 zz = *(const float4*)&xhat[(size_t)(NB + n)*4];
  float4 sg = *(const float4*)&sigma[(size_t)(NB + n)*4];

  for (int t = 0; t < T; ++t) {
    // software prefetch of next step's observation row
    int nr = (t + 2 <= TP1 - 1) ? (t + 2) : (TP1 - 1);
    float4 zn = *(const float4*)&xhat[((size_t)nr*NB + n)*4];
    float4 sn = *(const float4*)&sigma[((size_t)nr*NB + n)*4];

    // predict (wave-uniform)
    float mp[4];
#pragma unroll
    for (int r = 0; r < 4; ++r)
      mp[r] = b[r] + A[r][0]*m[0] + A[r][1]*m[1] + A[r][2]*m[2] + A[r][3]*m[3];
    float AP[4][4];
#pragma unroll
    for (int r = 0; r < 4; ++r)
#pragma unroll
      for (int c = 0; c < 4; ++c)
        AP[r][c] = A[r][0]*P[0][c] + A[r][1]*P[1][c] + A[r][2]*P[2][c] + A[r][3]*P[3][c];
    float Pp[4][4];
#pragma unroll
    for (int r = 0; r < 4; ++r)
#pragma unroll
      for (int c = r; c < 4; ++c) {
        float v = Q[r][c] + AP[r][0]*A[c][0] + AP[r][1]*A[c][1]
                          + AP[r][2]*A[c][2] + AP[r][3]*A[c][3];
        Pp[r][c] = v; Pp[c][r] = v;
      }

    // per-lane: S = Pp + diag(sigma_n); invert
    float S[4][4];
#pragma unroll
    for (int r = 0; r < 4; ++r)
#pragma unroll
      for (int c = 0; c < 4; ++c) S[r][c] = Pp[r][c];
    S[0][0] += sg.x; S[1][1] += sg.y; S[2][2] += sg.z; S[3][3] += sg.w;

    float Si[4][4];
    float det = inv4(S, Si);
    float logdet = __logf(det);

    float innov[4] = { zz.x - mp[0], zz.y - mp[1], zz.z - mp[2], zz.w - mp[3] };
    float sol[4];
#pragma unroll
    for (int r = 0; r < 4; ++r)
      sol[r] = Si[r][0]*innov[0] + Si[r][1]*innov[1] + Si[r][2]*innov[2] + Si[r][3]*innov[3];
    float quad = innov[0]*sol[0] + innov[1]*sol[1] + innov[2]*sol[2] + innov[3]*sol[3];
    float ll = -0.5f * (quad + logdet + 4.0f * LOG_2PI);

    float mx = wave_max(ll);
    float wi = __expf(ll - mx);

    // mi = mp + Pp*sol ; U = Pp*Si ; Pi = Pp - U*Pp
    float mi[4];
#pragma unroll
    for (int r = 0; r < 4; ++r)
      mi[r] = mp[r] + Pp[r][0]*sol[0] + Pp[r][1]*sol[1] + Pp[r][2]*sol[2] + Pp[r][3]*sol[3];
    float U[4][4];
#pragma unroll
    for (int r = 0; r < 4; ++r)
#pragma unroll
      for (int c = 0; c < 4; ++c)
        U[r][c] = Pp[r][0]*Si[0][c] + Pp[r][1]*Si[1][c] + Pp[r][2]*Si[2][c] + Pp[r][3]*Si[3][c];
    float Pi[4][4];
#pragma unroll
    for (int r = 0; r < 4; ++r)
#pragma unroll
      for (int c = r; c < 4; ++c) {
        float v = Pp[r][c] - (U[r][0]*Pp[0][c] + U[r][1]*Pp[1][c]
                            + U[r][2]*Pp[2][c] + U[r][3]*Pp[3][c]);
        Pi[r][c] = v; Pi[c][r] = v;
      }

    // reduce phase 1: W and w*mi
    float r0 = wave_sum(wi);
    float r1 = wave_sum(wi * mi[0]);
    float r2 = wave_sum(wi * mi[1]);
    float r3 = wave_sum(wi * mi[2]);
    float r4 = wave_sum(wi * mi[3]);
    float rW = __fdividef(1.0f, r0);
    float mu[4] = { r1*rW, r2*rW, r3*rW, r4*rW };
    float df[4] = { mi[0]-mu[0], mi[1]-mu[1], mi[2]-mu[2], mi[3]-mu[3] };

    // reduce phase 2: 10 upper entries of w*(Pi + df df^T)
    float a0 = wave_sum(wi * (Pi[0][0] + df[0]*df[0]));
    float a1 = wave_sum(wi * (Pi[0][1] + df[0]*df[1]));
    float a2 = wave_sum(wi * (Pi[0][2] + df[0]*df[2]));
    float a3 = wave_sum(wi * (Pi[0][3] + df[0]*df[3]));
    float a4 = wave_sum(wi * (Pi[1][1] + df[1]*df[1]));
    float a5 = wave_sum(wi * (Pi[1][2] + df[1]*df[2]));
    float a6 = wave_sum(wi * (Pi[1][3] + df[1]*df[3]));
    float a7 = wave_sum(wi * (Pi[2][2] + df[2]*df[2]));
    float a8 = wave_sum(wi * (Pi[2][3] + df[2]*df[3]));
    float a9 = wave_sum(wi * (Pi[3][3] + df[3]*df[3]));

    m[0]=mu[0]; m[1]=mu[1]; m[2]=mu[2]; m[3]=mu[3];
    P[0][0]=a0*rW; P[0][1]=a1*rW; P[0][2]=a2*rW; P[0][3]=a3*rW;
    P[1][0]=P[0][1]; P[1][1]=a4*rW; P[1][2]=a5*rW; P[1][3]=a6*rW;
    P[2][0]=P[0][2]; P[2][1]=P[1][2]; P[2][2]=a7*rW; P[2][3]=a8*rW;
    P[3][0]=P[0][3]; P[3][1]=P[1][3]; P[3][2]=P[2][3]; P[3][3]=a9*rW;

    if (n == 0) {
      *(float4*)&fm[((size_t)t*NB + i)*4] = make_float4(m[0], m[1], m[2], m[3]);
      float* fp = &fP[((size_t)t*NB + i)*16];
      *(float4*)&fp[0]  = make_float4(P[0][0],P[0][1],P[0][2],P[0][3]);
      *(float4*)&fp[4]  = make_float4(P[1][0],P[1][1],P[1][2],P[1][3]);
      *(float4*)&fp[8]  = make_float4(P[2][0],P[2][1],P[2][2],P[2][3]);
      *(float4*)&fp[12] = make_float4(P[3][0],P[3][1],P[3][2],P[3][3]);
    }
    zz = zn; sg = sn;
  }
}

// ==========================================================================
// Backward smoother as an affine suffix scan:
//   ms_t = c_t + G_t ms_{t+1} ; Ps_t = D_t + G_t Ps_{t+1} G_t^T
// ==========================================================================
struct Map { float G[4][4]; float c[4]; float Dm[4][4]; };

__device__ __forceinline__ void map_identity(Map& M) {
#pragma unroll
  for (int r = 0; r < 4; ++r) {
    M.c[r] = 0.f;
#pragma unroll
    for (int cc = 0; cc < 4; ++cc) { M.G[r][cc] = (r==cc)?1.f:0.f; M.Dm[r][cc] = 0.f; }
  }
}

// R = F ∘ S   (apply S first, then F); R may alias S
__device__ __forceinline__ void compose(const Map& F, const Map& Sm, Map& R) {
  float G[4][4], cv[4], V[4][4], Dn[4][4];
#pragma unroll
  for (int r = 0; r < 4; ++r)
#pragma unroll
    for (int c = 0; c < 4; ++c)
      G[r][c] = F.G[r][0]*Sm.G[0][c] + F.G[r][1]*Sm.G[1][c]
              + F.G[r][2]*Sm.G[2][c] + F.G[r][3]*Sm.G[3][c];
#pragma unroll
  for (int r = 0; r < 4; ++r)
    cv[r] = F.c[r] + F.G[r][0]*Sm.c[0] + F.G[r][1]*Sm.c[1]
                   + F.G[r][2]*Sm.c[2] + F.G[r][3]*Sm.c[3];
#pragma unroll
  for (int r = 0; r < 4; ++r)
#pragma unroll
    for (int c = 0; c < 4; ++c)
      V[r][c] = F.G[r][0]*Sm.Dm[0][c] + F.G[r][1]*Sm.Dm[1][c]
              + F.G[r][2]*Sm.Dm[2][c] + F.G[r][3]*Sm.Dm[3][c];
#pragma unroll
  for (int r = 0; r < 4; ++r)
#pragma unroll
    for (int c = r; c < 4; ++c) {
      float v = F.Dm[r][c] + V[r][0]*F.G[c][0] + V[r][1]*F.G[c][1]
                           + V[r][2]*F.G[c][2] + V[r][3]*F.G[c][3];
      Dn[r][c] = v; Dn[c][r] = v;
    }
#pragma unroll
  for (int r = 0; r < 4; ++r) {
    R.c[r] = cv[r];
#pragma unroll
    for (int c = 0; c < 4; ++c) { R.G[r][c] = G[r][c]; R.Dm[r][c] = Dn[r][c]; }
  }
}

// per-step map f_t for filter i (from forward results)
__device__ __forceinline__ void make_ft(int t, int i,
    const float* __restrict__ fm, const float* __restrict__ fP,
    const float A[4][4], const float b[4], const float Q[4][4], Map& M) {
  float4 mv = *(const float4*)&fm[((size_t)t*NB + i)*4];
  float mf[4] = { mv.x, mv.y, mv.z, mv.w };
  const float* fp = &fP[((size_t)t*NB + i)*16];
  float4 p0 = *(const float4*)&fp[0];
  float4 p1 = *(const float4*)&fp[4];
  float4 p2 = *(const float4*)&fp[8];
  float4 p3 = *(const float4*)&fp[12];
  float Pf[4][4] = {{p0.x,p0.y,p0.z,p0.w},{p1.x,p1.y,p1.z,p1.w},
                    {p2.x,p2.y,p2.z,p2.w},{p3.x,p3.y,p3.z,p3.w}};
  float mp[4];
#pragma unroll
  for (int r = 0; r < 4; ++r)
    mp[r] = b[r] + A[r][0]*mf[0] + A[r][1]*mf[1] + A[r][2]*mf[2] + A[r][3]*mf[3];
  float AP[4][4];
#pragma unroll
  for (int r = 0; r < 4; ++r)
#pragma unroll
    for (int c = 0; c < 4; ++c)
      AP[r][c] = A[r][0]*Pf[0][c] + A[r][1]*Pf[1][c] + A[r][2]*Pf[2][c] + A[r][3]*Pf[3][c];
  float Pp[4][4];
#pragma unroll
  for (int r = 0; r < 4; ++r)
#pragma unroll
    for (int c = r; c < 4; ++c) {
      float v = Q[r][c] + AP[r][0]*A[c][0] + AP[r][1]*A[c][1]
                        + AP[r][2]*A[c][2] + AP[r][3]*A[c][3];
      Pp[r][c] = v; Pp[c][r] = v;
    }
  float Ppi[4][4];
  inv4(Pp, Ppi);
  float W[4][4]; // Pf A^T
#pragma unroll
  for (int r = 0; r < 4; ++r)
#pragma unroll
    for (int c = 0; c < 4; ++c)
      W[r][c] = Pf[r][0]*A[c][0] + Pf[r][1]*A[c][1] + Pf[r][2]*A[c][2] + Pf[r][3]*A[c][3];
#pragma unroll
  for (int r = 0; r < 4; ++r)
#pragma unroll
    for (int c = 0; c < 4; ++c)
      M.G[r][c] = W[r][0]*Ppi[0][c] + W[r][1]*Ppi[1][c] + W[r][2]*Ppi[2][c] + W[r][3]*Ppi[3][c];
#pragma unroll
  for (int r = 0; r < 4; ++r)
    M.c[r] = mf[r] - (M.G[r][0]*mp[0] + M.G[r][1]*mp[1] + M.G[r][2]*mp[2] + M.G[r][3]*mp[3]);
  float V[4][4];
#pragma unroll
  for (int r = 0; r < 4; ++r)
#pragma unroll
    for (int c = 0; c < 4; ++c)
      V[r][c] = M.G[r][0]*Pp[0][c] + M.G[r][1]*Pp[1][c] + M.G[r][2]*Pp[2][c] + M.G[r][3]*Pp[3][c];
#pragma unroll
  for (int r = 0; r < 4; ++r)
#pragma unroll
    for (int c = r; c < 4; ++c) {
      float v = Pf[r][c] - (V[r][0]*M.G[c][0] + V[r][1]*M.G[c][1]
                          + V[r][2]*M.G[c][2] + V[r][3]*M.G[c][3]);
      M.Dm[r][c] = v; M.Dm[c][r] = v;
    }
}

__device__ __forceinline__ void store_map(float* __restrict__ p, const Map& M) {
  *(float4*)&p[0]  = make_float4(M.G[0][0],M.G[0][1],M.G[0][2],M.G[0][3]);
  *(float4*)&p[4]  = make_float4(M.G[1][0],M.G[1][1],M.G[1][2],M.G[1][3]);
  *(float4*)&p[8]  = make_float4(M.G[2][0],M.G[2][1],M.G[2][2],M.G[2][3]);
  *(float4*)&p[12] = make_float4(M.G[3][0],M.G[3][1],M.G[3][2],M.G[3][3]);
  *(float4*)&p[16] = make_float4(M.c[0],M.c[1],M.c[2],M.c[3]);
  *(float4*)&p[20] = make_float4(M.Dm[0][0],M.Dm[0][1],M.Dm[0][2],M.Dm[0][3]);
  *(float4*)&p[24] = make_float4(M.Dm[1][0],M.Dm[1][1],M.Dm[1][2],M.Dm[1][3]);
  *(float4*)&p[28] = make_float4(M.Dm[2][0],M.Dm[2][1],M.Dm[2][2],M.Dm[2][3]);
  *(float4*)&p[32] = make_float4(M.Dm[3][0],M.Dm[3][1],M.Dm[3][2],M.Dm[3][3]);
}
__device__ __forceinline__ void load_map(const float* __restrict__ p, Map& M) {
  float4 g0=*(const float4*)&p[0], g1=*(const float4*)&p[4],
         g2=*(const float4*)&p[8], g3=*(const float4*)&p[12];
  float4 cv=*(const float4*)&p[16];
  float4 d0=*(const float4*)&p[20], d1=*(const float4*)&p[24],
         d2=*(const float4*)&p[28], d3=*(const float4*)&p[32];
  M.G[0][0]=g0.x;M.G[0][1]=g0.y;M.G[0][2]=g0.z;M.G[0][3]=g0.w;
  M.G[1][0]=g1.x;M.G[1][1]=g1.y;M.G[1][2]=g1.z;M.G[1][3]=g1.w;
  M.G[2][0]=g2.x;M.G[2][1]=g2.y;M.G[2][2]=g2.z;M.G[2][3]=g2.w;
  M.G[3][0]=g3.x;M.G[3][1]=g3.y;M.G[3][2]=g3.z;M.G[3][3]=g3.w;
  M.c[0]=cv.x;M.c[1]=cv.y;M.c[2]=cv.z;M.c[3]=cv.w;
  M.Dm[0][0]=d0.x;M.Dm[0][1]=d0.y;M.Dm[0][2]=d0.z;M.Dm[0][3]=d0.w;
  M.Dm[1][0]=d1.x;M.Dm[1][1]=d1.y;M.Dm[1][2]=d1.z;M.Dm[1][3]=d1.w;
  M.Dm[2][0]=d2.x;M.Dm[2][1]=d2.y;M.Dm[2][2]=d2.z;M.Dm[2][3]=d2.w;
  M.Dm[3][0]=d3.x;M.Dm[3][1]=d3.y;M.Dm[3][2]=d3.z;M.Dm[3][3]=d3.w;
}

// K3 phase A: per (chunk, filter) compose chunk aggregate right-to-left
__global__ void __launch_bounds__(64, 1) k_phaseA(
    const float* __restrict__ fm, const float* __restrict__ fP,
    const float* __restrict__ Ag, const float* __restrict__ bg,
    const float* __restrict__ qp, float* __restrict__ Cw) {
  const int cc = blockIdx.x;  // chunk
  const int i  = threadIdx.x; // filter
  float A[4][4], Q[4][4], b[4];
  load_A_b_Q(Ag, bg, qp, A, b, Q);
  Map agg; map_identity(agg);
  int a = cc * CLEN;
  int bb = a + CLEN - 1; if (bb > T - 2) bb = T - 2;
  for (int t = bb; t >= a; --t) {
    Map f; make_ft(t, i, fm, fP, A, b, Q, f);
    compose(f, agg, agg);
  }
  store_map(&Cw[((size_t)i*CH + cc)*36], agg);
}

// K4 phase B: per filter, exclusive suffix scan of chunk aggregates
__global__ void __launch_bounds__(64, 1) k_phaseB(
    const float* __restrict__ Cw, float* __restrict__ Ew) {
  const int i = threadIdx.x;
  Map agg; map_identity(agg);
  for (int cc = CH - 1; cc >= 0; --cc) {
    store_map(&Ew[((size_t)i*CH + cc)*36], agg);
    Map Cc; load_map(&Cw[((size_t)i*CH + cc)*36], Cc);
    compose(Cc, agg, agg);
  }
}

// cholesky of sP+1e-5 I, z = sm + L eps, out = z @ dec_w + dec_b
__device__ __forceinline__ void recon(int t, int i,
    const float sm[4], const float sP[4][4],
    const float* __restrict__ eps, const float* __restrict__ dw,
    const float* __restrict__ db, float* __restrict__ out) {
  float a00 = sP[0][0]+1e-5f, a11 = sP[1][1]+1e-5f, a22 = sP[2][2]+1e-5f, a33 = sP[3][3]+1e-5f;
  float L00 = sqrtf(a00);
  float r0 = __fdividef(1.0f, L00);
  float L10 = sP[1][0]*r0, L20 = sP[2][0]*r0, L30 = sP[3][0]*r0;
  float L11 = sqrtf(a11 - L10*L10);
  float r1 = __fdividef(1.0f, L11);
  float L21 = (sP[2][1]-L20*L10)*r1, L31 = (sP[3][1]-L30*L10)*r1;
  float L22 = sqrtf(a22 - L20*L20 - L21*L21);
  float r2 = __fdividef(1.0f, L22);
  float L32 = (sP[3][2]-L30*L20-L31*L21)*r2;
  float L33 = sqrtf(a33 - L30*L30 - L31*L31 - L32*L32);
  float4 e = *(const float4*)&eps[((size_t)t*NB + i)*4];
  float z0 = sm[0] + L00*e.x;
  float z1 = sm[1] + L10*e.x + L11*e.y;
  float z2 = sm[2] + L20*e.x + L21*e.y + L22*e.z;
  float z3 = sm[3] + L30*e.x + L31*e.y + L32*e.z + L33*e.w;
#pragma unroll
  for (int p = 0; p < 3; ++p)
    out[((size_t)t*NB + i)*3 + p] =
        db[p] + z0*dw[0*3+p] + z1*dw[1*3+p] + z2*dw[2*3+p] + z3*dw[3*3+p];
}

// K5 phase C: apply exclusive suffix, walk chunk downward emitting sm/sP + recon
__global__ void __launch_bounds__(64, 1) k_phaseC(
    const float* __restrict__ fm, const float* __restrict__ fP,
    const float* __restrict__ Ew,
    const float* __restrict__ Ag, const float* __restrict__ bg,
    const float* __restrict__ qp,
    const float* __restrict__ eps, const float* __restrict__ dw,
    const float* __restrict__ db, float* __restrict__ out) {
  const int cc = blockIdx.x;
  const int i  = threadIdx.x;
  float A[4][4], Q[4][4], b[4];
  load_A_b_Q(Ag, bg, qp, A, b, Q);

  // final filtered state (t = T-1) == final smoothed state
  float4 mv = *(const float4*)&fm[((size_t)(T-1)*NB + i)*4];
  float mT[4] = { mv.x, mv.y, mv.z, mv.w };
  const float* fpT = &fP[((size_t)(T-1)*NB + i)*16];
  float4 p0=*(const float4*)&fpT[0], p1=*(const float4*)&fpT[4],
         p2=*(const float4*)&fpT[8], p3=*(const float4*)&fpT[12];
  float PT[4][4] = {{p0.x,p0.y,p0.z,p0.w},{p1.x,p1.y,p1.z,p1.w},
                    {p2.x,p2.y,p2.z,p2.w},{p3.x,p3.y,p3.z,p3.w}};

  Map E; load_map(&Ew[((size_t)i*CH + cc)*36], E);

  // state = E(s_final) : smoothed state at t = first index of chunk cc+1
  float sm[4], sP[4][4];
#pragma unroll
  for (int r = 0; r < 4; ++r)
    sm[r] = E.c[r] + E.G[r][0]*mT[0] + E.G[r][1]*mT[1] + E.G[r][2]*mT[2] + E.G[r][3]*mT[3];
  {
    float V[4][4];
#pragma unroll
    for (int r = 0; r < 4; ++r)
#pragma unroll
      for (int c = 0; c < 4; ++c)
        V[r][c] = E.G[r][0]*PT[0][c] + E.G[r][1]*PT[1][c] + E.G[r][2]*PT[2][c] + E.G[r][3]*PT[3][c];
#pragma unroll
    for (int r = 0; r < 4; ++r)
#pragma unroll
      for (int c = r; c < 4; ++c) {
        float v = E.Dm[r][c] + V[r][0]*E.G[c][0] + V[r][1]*E.G[c][1]
                             + V[r][2]*E.G[c][2] + V[r][3]*E.G[c][3];
        sP[r][c] = v; sP[c][r] = v;
      }
  }

  if (cc == CH - 1) recon(T - 1, i, mT, PT, eps, dw, db, out);

  int a = cc * CLEN;
  int bb = a + CLEN - 1; if (bb > T - 2) bb = T - 2;
  for (int t = bb; t >= a; --t) {
    Map f; make_ft(t, i, fm, fP, A, b, Q, f);
    float smn[4];
#pragma unroll
    for (int r = 0; r < 4; ++r)
      smn[r] = f.c[r] + f.G[r][0]*sm[0] + f.G[r][1]*sm[1] + f.G[r][2]*sm[2] + f.G[r][3]*sm[3];
    float V[4][4];
#pragma unroll
    for (int r = 0; r < 4; ++r)
#pragma unroll
      for (int c = 0; c < 4; ++c)
        V[r][c] = f.G[r][0]*sP[0][c] + f.G[r][1]*sP[1][c] + f.G[r][2]*sP[2][c] + f.G[r][3]*sP[3][c];
#pragma unroll
    for (int r = 0; r < 4; ++r)
#pragma unroll
      for (int c = r; c < 4; ++c) {
        float v = f.Dm[r][c] + V[r][0]*f.G[c][0] + V[r][1]*f.G[c][1]
                             + V[r][2]*f.G[c][2] + V[r][3]*f.G[c][3];
        sP[r][c] = v; sP[c][r] = v;
      }
    sm[0]=smn[0]; sm[1]=smn[1]; sm[2]=smn[2]; sm[3]=smn[3];
    recon(t, i, sm, sP, eps, dw, db, out);
  }
}

// ==========================================================================
extern "C" void kernel_launch(void* const* d_in, const int* in_sizes, int n_in,
                              void* d_out, int out_size, void* d_ws, size_t ws_size,
                              hipStream_t stream) {
  const float* x   = (const float*)d_in[0];
  const float* eps = (const float*)d_in[1];
  const float* w1  = (const float*)d_in[2];
  const float* b1  = (const float*)d_in[3];
  const float* wx  = (const float*)d_in[4];
  const float* bx  = (const float*)d_in[5];
  const float* wl  = (const float*)d_in[6];
  const float* bl  = (const float*)d_in[7];
  const float* dw  = (const float*)d_in[8];
  const float* db  = (const float*)d_in[9];
  const float* Ag  = (const float*)d_in[10];
  const float* bg  = (const float*)d_in[11];
  const float* qp  = (const float*)d_in[12];

  float* ws    = (float*)d_ws;
  float* xhat  = ws + OFF_XHAT;
  float* sigma = ws + OFF_SIGMA;
  float* fm    = ws + OFF_FM;
  float* fP    = ws + OFF_FP;
  float* Cw    = ws + OFF_C;
  float* Ew    = ws + OFF_E;
  float* out   = (float*)d_out;

  k_encoder<<<(TP1*NB + 255)/256, 256, 0, stream>>>(x, w1, b1, wx, bx, wl, bl, xhat, sigma);
  k_filter<<<NB, NB, 0, stream>>>(xhat, sigma, Ag, bg, qp, fm, fP);
  k_phaseA<<<CH, NB, 0, stream>>>(fm, fP, Ag, bg, qp, Cw);
  k_phaseB<<<1, NB, 0, stream>>>(Cw, Ew);
  k_phaseC<<<CH, NB, 0, stream>>>(fm, fP, Ew, Ag, bg, qp, eps, dw, db, out);
}

// Round 2
// 3469.683 us; speedup vs baseline: 1.0448x; 1.0448x over previous
//
#include <hip/hip_runtime.h>
#include <math.h>

#define D4   4
#define NB   64      // batch = #filters = #observations
#define T    2048
#define TP1  2049
#define HID  20
#define POS  3
#define CH   64      // chunks for backward parallel scan
#define CLEN 32      // chunk length (CH*CLEN >= T-1)

#define LOG_2PI 1.8378770664093453f
#define TWO_LOG_2PI 3.6757541328186906f

// ---- workspace layout (floats) -------------------------------------------
#define OFF_XHAT  0
#define OFF_SIGMA (TP1*NB*4)
#define OFF_FM    (2*TP1*NB*4)
#define OFF_FP    (OFF_FM + T*NB*4)
#define OFF_C     (OFF_FP + T*NB*16)
#define OFF_E     (OFF_C + NB*CH*36)

// ---- DPP wave reductions (VALU pipe, no LDS) ------------------------------
// sum chain: row_shr 1/2/4/8 then row_bcast:15 (rows 1,3), row_bcast:31
// (rows 2,3); total lands in lane 63; broadcast via readlane (SGPR).
template<int CTRL, int RM>
__device__ __forceinline__ float dpp_sum_step(float v) {
  int t = __builtin_amdgcn_update_dpp(0, __float_as_int(v), CTRL, RM, 0xF, true);
  return v + __int_as_float(t);
}
template<int CTRL, int RM>
__device__ __forceinline__ float dpp_max_step(float v) {
  int vi = __float_as_int(v);
  int t = __builtin_amdgcn_update_dpp(vi, vi, CTRL, RM, 0xF, false);
  return fmaxf(v, __int_as_float(t));
}
__device__ __forceinline__ float wsum(float v) {
  v = dpp_sum_step<0x111, 0xF>(v);   // row_shr:1
  v = dpp_sum_step<0x112, 0xF>(v);   // row_shr:2
  v = dpp_sum_step<0x114, 0xF>(v);   // row_shr:4
  v = dpp_sum_step<0x118, 0xF>(v);   // row_shr:8
  v = dpp_sum_step<0x142, 0xA>(v);   // row_bcast:15 into rows 1,3
  v = dpp_sum_step<0x143, 0xC>(v);   // row_bcast:31 into rows 2,3
  return __int_as_float(__builtin_amdgcn_readlane(__float_as_int(v), 63));
}
__device__ __forceinline__ float wmax(float v) {
  v = dpp_max_step<0x111, 0xF>(v);
  v = dpp_max_step<0x112, 0xF>(v);
  v = dpp_max_step<0x114, 0xF>(v);
  v = dpp_max_step<0x118, 0xF>(v);
  v = dpp_max_step<0x142, 0xA>(v);
  v = dpp_max_step<0x143, 0xC>(v);
  return __int_as_float(__builtin_amdgcn_readlane(__float_as_int(v), 63));
}

// ---- 4x4 inverse (adjugate, general); returns det ------------------------
__device__ __forceinline__ float inv4(const float a[4][4], float inv[4][4]) {
  float s0 = a[0][0]*a[1][1] - a[1][0]*a[0][1];
  float s1 = a[0][0]*a[1][2] - a[1][0]*a[0][2];
  float s2 = a[0][0]*a[1][3] - a[1][0]*a[0][3];
  float s3 = a[0][1]*a[1][2] - a[1][1]*a[0][2];
  float s4 = a[0][1]*a[1][3] - a[1][1]*a[0][3];
  float s5 = a[0][2]*a[1][3] - a[1][2]*a[0][3];
  float c5 = a[2][2]*a[3][3] - a[3][2]*a[2][3];
  float c4 = a[2][1]*a[3][3] - a[3][1]*a[2][3];
  float c3 = a[2][1]*a[3][2] - a[3][1]*a[2][2];
  float c2 = a[2][0]*a[3][3] - a[3][0]*a[2][3];
  float c1 = a[2][0]*a[3][2] - a[3][0]*a[2][2];
  float c0 = a[2][0]*a[3][1] - a[3][0]*a[2][1];
  float det = s0*c5 - s1*c4 + s2*c3 + s3*c2 - s4*c1 + s5*c0;
  float id = __fdividef(1.0f, det);
  inv[0][0] = ( a[1][1]*c5 - a[1][2]*c4 + a[1][3]*c3) * id;
  inv[0][1] = (-a[0][1]*c5 + a[0][2]*c4 - a[0][3]*c3) * id;
  inv[0][2] = ( a[3][1]*s5 - a[3][2]*s4 + a[3][3]*s3) * id;
  inv[0][3] = (-a[2][1]*s5 + a[2][2]*s4 - a[2][3]*s3) * id;
  inv[1][0] = (-a[1][0]*c5 + a[1][2]*c2 - a[1][3]*c1) * id;
  inv[1][1] = ( a[0][0]*c5 - a[0][2]*c2 + a[0][3]*c1) * id;
  inv[1][2] = (-a[3][0]*s5 + a[3][2]*s2 - a[3][3]*s1) * id;
  inv[1][3] = ( a[2][0]*s5 - a[2][2]*s2 + a[2][3]*s1) * id;
  inv[2][0] = ( a[1][0]*c4 - a[1][1]*c2 + a[1][3]*c0) * id;
  inv[2][1] = (-a[0][0]*c4 + a[0][1]*c2 - a[0][3]*c0) * id;
  inv[2][2] = ( a[3][0]*s4 - a[3][1]*s2 + a[3][3]*s0) * id;
  inv[2][3] = (-a[2][0]*s4 + a[2][1]*s2 - a[2][3]*s0) * id;
  inv[3][0] = (-a[1][0]*c3 + a[1][1]*c1 - a[1][2]*c0) * id;
  inv[3][1] = ( a[0][0]*c3 - a[0][1]*c1 + a[0][2]*c0) * id;
  inv[3][2] = (-a[3][0]*s3 + a[3][1]*s1 - a[3][2]*s0) * id;
  inv[3][3] = ( a[2][0]*s3 - a[2][1]*s1 + a[2][2]*s0) * id;
  return det;
}

// ---- Q = L L^T from q_param (tril_indices row-major order) ---------------
__device__ __forceinline__ void build_Q(const float* __restrict__ qp, float Q[4][4]) {
  float L[4][4] = {{0.f,0.f,0.f,0.f},{0.f,0.f,0.f,0.f},{0.f,0.f,0.f,0.f},{0.f,0.f,0.f,0.f}};
  L[0][0] = expf(qp[0]);
  L[1][0] = qp[1]; L[1][1] = expf(qp[2]);
  L[2][0] = qp[3]; L[2][1] = qp[4]; L[2][2] = expf(qp[5]);
  L[3][0] = qp[6]; L[3][1] = qp[7]; L[3][2] = qp[8]; L[3][3] = expf(qp[9]);
#pragma unroll
  for (int r = 0; r < 4; ++r)
#pragma unroll
    for (int c = 0; c < 4; ++c) {
      float v = 0.f;
#pragma unroll
      for (int k = 0; k < 4; ++k) v += L[r][k] * L[c][k];
      Q[r][c] = v;
    }
}

__device__ __forceinline__ void load_A_b_Q(const float* __restrict__ Ag,
                                           const float* __restrict__ bg,
                                           const float* __restrict__ qp,
                                           float A[4][4], float b[4], float Q[4][4]) {
#pragma unroll
  for (int r = 0; r < 4; ++r) {
    b[r] = bg[r];
#pragma unroll
    for (int c = 0; c < 4; ++c) A[r][c] = Ag[r * 4 + c];
  }
  build_Q(qp, Q);
}

// ==========================================================================
// K1: encoder — xhat, sigma for all (t,n)
// ==========================================================================
__global__ void k_encoder(const float* __restrict__ x,
                          const float* __restrict__ w1, const float* __restrict__ b1,
                          const float* __restrict__ wx, const float* __restrict__ bx,
                          const float* __restrict__ wl, const float* __restrict__ bl,
                          float* __restrict__ xhat, float* __restrict__ sigma) {
  int idx = blockIdx.x * blockDim.x + threadIdx.x;
  if (idx >= TP1 * NB) return;
  float x0 = x[idx*3+0], x1 = x[idx*3+1], x2 = x[idx*3+2];
  float xh[4], lm[4];
#pragma unroll
  for (int k = 0; k < 4; ++k) { xh[k] = bx[k]; lm[k] = bl[k]; }
#pragma unroll
  for (int j = 0; j < HID; ++j) {
    float h = x0*w1[0*HID+j] + x1*w1[1*HID+j] + x2*w1[2*HID+j] + b1[j];
    h = fmaxf(h, 0.0f);
#pragma unroll
    for (int k = 0; k < 4; ++k) { xh[k] += h * wx[j*4+k]; lm[k] += h * wl[j*4+k]; }
  }
  *(float4*)&xhat[(size_t)idx*4]  = make_float4(xh[0], xh[1], xh[2], xh[3]);
  *(float4*)&sigma[(size_t)idx*4] = make_float4(expf(0.5f*lm[0]), expf(0.5f*lm[1]),
                                                expf(0.5f*lm[2]), expf(0.5f*lm[3]));
}

// ==========================================================================
// K2: forward mixture Kalman filter — one wave per filter, lane = observation
//   - merged covariance reduction:  P = (Σw(Pi+mi miᵀ))/W − mu muᵀ
//   - Pi = Pp·S⁻¹·R with R diagonal → Pi[r][c] = U[r][c]·σ_c
//   - symmetric adjugate inverse, upper triangle only
//   - all reductions via DPP chain + readlane (single phase of 15 + max)
// ==========================================================================
__global__ void __launch_bounds__(64, 1) k_filter(
    const float* __restrict__ xhat, const float* __restrict__ sigma,
    const float* __restrict__ Ag, const float* __restrict__ bg,
    const float* __restrict__ qp,
    float* __restrict__ fm, float* __restrict__ fP) {
  const int fi = blockIdx.x;  // filter
  const int n  = threadIdx.x; // observation lane

  float A[4][4], Q[4][4], bv[4];
  load_A_b_Q(Ag, bg, qp, A, bv, Q);

  float m[4], P[4][4];
  {
    float4 m0 = *(const float4*)&xhat[fi*4];
    float4 s0 = *(const float4*)&sigma[fi*4];
    m[0]=m0.x; m[1]=m0.y; m[2]=m0.z; m[3]=m0.w;
#pragma unroll
    for (int r = 0; r < 4; ++r)
#pragma unroll
      for (int c = 0; c < 4; ++c) P[r][c] = 0.0f;
    P[0][0]=s0.x; P[1][1]=s0.y; P[2][2]=s0.z; P[3][3]=s0.w;
  }

  // preload obs row 1 (step t uses row t+1)
  float4 zz = *(const float4*)&xhat[(size_t)(NB + n)*4];
  float4 sgc = *(const float4*)&sigma[(size_t)(NB + n)*4];

  for (int t = 0; t < T; ++t) {
    // software prefetch of next step's observation row
    int nr = (t + 2 <= TP1 - 1) ? (t + 2) : (TP1 - 1);
    float4 zn  = *(const float4*)&xhat[((size_t)nr*NB + n)*4];
    float4 sgn = *(const float4*)&sigma[((size_t)nr*NB + n)*4];

    // ---- predict (wave-uniform) ----
    float mp[4];
#pragma unroll
    for (int r = 0; r < 4; ++r)
      mp[r] = bv[r] + A[r][0]*m[0] + A[r][1]*m[1] + A[r][2]*m[2] + A[r][3]*m[3];
    float AP[4][4];
#pragma unroll
    for (int r = 0; r < 4; ++r)
#pragma unroll
      for (int c = 0; c < 4; ++c)
        AP[r][c] = A[r][0]*P[0][c] + A[r][1]*P[1][c] + A[r][2]*P[2][c] + A[r][3]*P[3][c];
    float Pp[4][4];
#pragma unroll
    for (int r = 0; r < 4; ++r)
#pragma unroll
      for (int c = r; c < 4; ++c) {
        float v = Q[r][c] + AP[r][0]*A[c][0] + AP[r][1]*A[c][1]
                          + AP[r][2]*A[c][2] + AP[r][3]*A[c][3];
        Pp[r][c] = v; Pp[c][r] = v;
      }

    // ---- per-lane: S = Pp + diag(sigma); symmetric adjugate inverse ----
    float s00 = Pp[0][0] + sgc.x, s11 = Pp[1][1] + sgc.y,
          s22 = Pp[2][2] + sgc.z, s33 = Pp[3][3] + sgc.w;
    float s01 = Pp[0][1], s02 = Pp[0][2], s03 = Pp[0][3],
          s12 = Pp[1][2], s13 = Pp[1][3], s23 = Pp[2][3];

    float m0_ = s00*s11 - s01*s01;
    float m1_ = s00*s12 - s01*s02;
    float m2_ = s00*s13 - s01*s03;
    float m3_ = s01*s12 - s11*s02;
    float m4_ = s01*s13 - s11*s03;
    float m5_ = s02*s13 - s12*s03;   // == c0 by symmetry
    float n5_ = s22*s33 - s23*s23;
    float n4_ = s12*s33 - s13*s23;
    float n3_ = s12*s23 - s13*s22;
    float n2_ = s02*s33 - s03*s23;
    float n1_ = s02*s23 - s03*s22;
    float det = m0_*n5_ - m1_*n4_ + m2_*n3_ + m3_*n2_ - m4_*n1_ + m5_*m5_;
    float id  = __fdividef(1.0f, det);
    float i00 = ( s11*n5_ - s12*n4_ + s13*n3_) * id;
    float i01 = (-s01*n5_ + s02*n4_ - s03*n3_) * id;
    float i02 = ( s13*m5_ - s23*m4_ + s33*m3_) * id;
    float i03 = (-s12*m5_ + s22*m4_ - s23*m3_) * id;
    float i11 = ( s00*n5_ - s02*n2_ + s03*n1_) * id;
    float i12 = (-s03*m5_ + s23*m2_ - s33*m1_) * id;
    float i13 = ( s02*m5_ - s22*m2_ + s23*m1_) * id;
    float i22 = ( s03*m4_ - s13*m2_ + s33*m0_) * id;
    float i23 = (-s02*m4_ + s12*m2_ - s23*m0_) * id;
    float i33 = ( s02*m3_ - s12*m1_ + s22*m0_) * id;
    float Si_[4][4] = {{i00,i01,i02,i03},{i01,i11,i12,i13},
                       {i02,i12,i22,i23},{i03,i13,i23,i33}};
    float logdet = __logf(det);

    float iv0 = zz.x - mp[0], iv1 = zz.y - mp[1],
          iv2 = zz.z - mp[2], iv3 = zz.w - mp[3];
    float y0 = i00*iv0 + i01*iv1 + i02*iv2 + i03*iv3;
    float y1 = i01*iv0 + i11*iv1 + i12*iv2 + i13*iv3;
    float y2 = i02*iv0 + i12*iv1 + i22*iv2 + i23*iv3;
    float y3 = i03*iv0 + i13*iv1 + i23*iv2 + i33*iv3;
    float quad = iv0*y0 + iv1*y1 + iv2*y2 + iv3*y3;
    float ll = -0.5f*(quad + logdet) - TWO_LOG_2PI;

    // max-reduce overlaps with the wi-independent algebra below
    float M = wmax(ll);

    // mi = mp + Pp*y
    float mi0 = mp[0] + Pp[0][0]*y0 + Pp[0][1]*y1 + Pp[0][2]*y2 + Pp[0][3]*y3;
    float mi1 = mp[1] + Pp[1][0]*y0 + Pp[1][1]*y1 + Pp[1][2]*y2 + Pp[1][3]*y3;
    float mi2 = mp[2] + Pp[2][0]*y0 + Pp[2][1]*y1 + Pp[2][2]*y2 + Pp[2][3]*y3;
    float mi3 = mp[3] + Pp[3][0]*y0 + Pp[3][1]*y1 + Pp[3][2]*y2 + Pp[3][3]*y3;

    // X = Pi + mi miᵀ, upper;  Pi[r][c] = (Pp·Si)[r][c] * sigma_c
    const float sd0 = sgc.x, sd1 = sgc.y, sd2 = sgc.z, sd3 = sgc.w;
#define UE(r,c) (Pp[r][0]*Si_[0][c] + Pp[r][1]*Si_[1][c] + Pp[r][2]*Si_[2][c] + Pp[r][3]*Si_[3][c])
    float X00 = UE(0,0)*sd0 + mi0*mi0;
    float X01 = UE(0,1)*sd1 + mi0*mi1;
    float X02 = UE(0,2)*sd2 + mi0*mi2;
    float X03 = UE(0,3)*sd3 + mi0*mi3;
    float X11 = UE(1,1)*sd1 + mi1*mi1;
    float X12 = UE(1,2)*sd2 + mi1*mi2;
    float X13 = UE(1,3)*sd3 + mi1*mi3;
    float X22 = UE(2,2)*sd2 + mi2*mi2;
    float X23 = UE(2,3)*sd3 + mi2*mi3;
    float X33 = UE(3,3)*sd3 + mi3*mi3;
#undef UE

    float wi = __expf(ll - M);

    // ---- single reduction phase: 15 independent DPP chains ----
    float W   = wsum(wi);
    float wm0 = wsum(wi*mi0);
    float wm1 = wsum(wi*mi1);
    float wm2 = wsum(wi*mi2);
    float wm3 = wsum(wi*mi3);
    float q00 = wsum(wi*X00);
    float q01 = wsum(wi*X01);
    float q02 = wsum(wi*X02);
    float q03 = wsum(wi*X03);
    float q11 = wsum(wi*X11);
    float q12 = wsum(wi*X12);
    float q13 = wsum(wi*X13);
    float q22 = wsum(wi*X22);
    float q23 = wsum(wi*X23);
    float q33 = wsum(wi*X33);

    float rW = __fdividef(1.0f, W);
    float mu0 = wm0*rW, mu1 = wm1*rW, mu2 = wm2*rW, mu3 = wm3*rW;
    m[0]=mu0; m[1]=mu1; m[2]=mu2; m[3]=mu3;
    P[0][0] = q00*rW - mu0*mu0;
    P[0][1] = q01*rW - mu0*mu1;  P[1][0] = P[0][1];
    P[0][2] = q02*rW - mu0*mu2;  P[2][0] = P[0][2];
    P[0][3] = q03*rW - mu0*mu3;  P[3][0] = P[0][3];
    P[1][1] = q11*rW - mu1*mu1;
    P[1][2] = q12*rW - mu1*mu2;  P[2][1] = P[1][2];
    P[1][3] = q13*rW - mu1*mu3;  P[3][1] = P[1][3];
    P[2][2] = q22*rW - mu2*mu2;
    P[2][3] = q23*rW - mu2*mu3;  P[3][2] = P[2][3];
    P[3][3] = q33*rW - mu3*mu3;

    if (n == 0) {
      *(float4*)&fm[((size_t)t*NB + fi)*4] = make_float4(m[0], m[1], m[2], m[3]);
      float* fp = &fP[((size_t)t*NB + fi)*16];
      *(float4*)&fp[0]  = make_float4(P[0][0],P[0][1],P[0][2],P[0][3]);
      *(float4*)&fp[4]  = make_float4(P[1][0],P[1][1],P[1][2],P[1][3]);
      *(float4*)&fp[8]  = make_float4(P[2][0],P[2][1],P[2][2],P[2][3]);
      *(float4*)&fp[12] = make_float4(P[3][0],P[3][1],P[3][2],P[3][3]);
    }
    zz = zn; sgc = sgn;
  }
}

// ==========================================================================
// Backward smoother as an affine suffix scan:
//   ms_t = c_t + G_t ms_{t+1} ; Ps_t = D_t + G_t Ps_{t+1} G_t^T
// ==========================================================================
struct Map { float G[4][4]; float c[4]; float Dm[4][4]; };

__device__ __forceinline__ void map_identity(Map& M) {
#pragma unroll
  for (int r = 0; r < 4; ++r) {
    M.c[r] = 0.f;
#pragma unroll
    for (int cc = 0; cc < 4; ++cc) { M.G[r][cc] = (r==cc)?1.f:0.f; M.Dm[r][cc] = 0.f; }
  }
}

// R = F ∘ S   (apply S first, then F); R may alias S
__device__ __forceinline__ void compose(const Map& F, const Map& Sm, Map& R) {
  float G[4][4], cv[4], V[4][4], Dn[4][4];
#pragma unroll
  for (int r = 0; r < 4; ++r)
#pragma unroll
    for (int c = 0; c < 4; ++c)
      G[r][c] = F.G[r][0]*Sm.G[0][c] + F.G[r][1]*Sm.G[1][c]
              + F.G[r][2]*Sm.G[2][c] + F.G[r][3]*Sm.G[3][c];
#pragma unroll
  for (int r = 0; r < 4; ++r)
    cv[r] = F.c[r] + F.G[r][0]*Sm.c[0] + F.G[r][1]*Sm.c[1]
                   + F.G[r][2]*Sm.c[2] + F.G[r][3]*Sm.c[3];
#pragma unroll
  for (int r = 0; r < 4; ++r)
#pragma unroll
    for (int c = 0; c < 4; ++c)
      V[r][c] = F.G[r][0]*Sm.Dm[0][c] + F.G[r][1]*Sm.Dm[1][c]
              + F.G[r][2]*Sm.Dm[2][c] + F.G[r][3]*Sm.Dm[3][c];
#pragma unroll
  for (int r = 0; r < 4; ++r)
#pragma unroll
    for (int c = r; c < 4; ++c) {
      float v = F.Dm[r][c] + V[r][0]*F.G[c][0] + V[r][1]*F.G[c][1]
                           + V[r][2]*F.G[c][2] + V[r][3]*F.G[c][3];
      Dn[r][c] = v; Dn[c][r] = v;
    }
#pragma unroll
  for (int r = 0; r < 4; ++r) {
    R.c[r] = cv[r];
#pragma unroll
    for (int c = 0; c < 4; ++c) { R.G[r][c] = G[r][c]; R.Dm[r][c] = Dn[r][c]; }
  }
}

// per-step map f_t for filter i (from forward results)
__device__ __forceinline__ void make_ft(int t, int i,
    const float* __restrict__ fm, const float* __restrict__ fP,
    const float A[4][4], const float b[4], const float Q[4][4], Map& M) {
  float4 mv = *(const float4*)&fm[((size_t)t*NB + i)*4];
  float mf[4] = { mv.x, mv.y, mv.z, mv.w };
  const float* fp = &fP[((size_t)t*NB + i)*16];
  float4 p0 = *(const float4*)&fp[0];
  float4 p1 = *(const float4*)&fp[4];
  float4 p2 = *(const float4*)&fp[8];
  float4 p3 = *(const float4*)&fp[12];
  float Pf[4][4] = {{p0.x,p0.y,p0.z,p0.w},{p1.x,p1.y,p1.z,p1.w},
                    {p2.x,p2.y,p2.z,p2.w},{p3.x,p3.y,p3.z,p3.w}};
  float mp[4];
#pragma unroll
  for (int r = 0; r < 4; ++r)
    mp[r] = b[r] + A[r][0]*mf[0] + A[r][1]*mf[1] + A[r][2]*mf[2] + A[r][3]*mf[3];
  float AP[4][4];
#pragma unroll
  for (int r = 0; r < 4; ++r)
#pragma unroll
    for (int c = 0; c < 4; ++c)
      AP[r][c] = A[r][0]*Pf[0][c] + A[r][1]*Pf[1][c] + A[r][2]*Pf[2][c] + A[r][3]*Pf[3][c];
  float Pp[4][4];
#pragma unroll
  for (int r = 0; r < 4; ++r)
#pragma unroll
    for (int c = r; c < 4; ++c) {
      float v = Q[r][c] + AP[r][0]*A[c][0] + AP[r][1]*A[c][1]
                        + AP[r][2]*A[c][2] + AP[r][3]*A[c][3];
      Pp[r][c] = v; Pp[c][r] = v;
    }
  float Ppi[4][4];
  inv4(Pp, Ppi);
  float W[4][4]; // Pf A^T
#pragma unroll
  for (int r = 0; r < 4; ++r)
#pragma unroll
    for (int c = 0; c < 4; ++c)
      W[r][c] = Pf[r][0]*A[c][0] + Pf[r][1]*A[c][1] + Pf[r][2]*A[c][2] + Pf[r][3]*A[c][3];
#pragma unroll
  for (int r = 0; r < 4; ++r)
#pragma unroll
    for (int c = 0; c < 4; ++c)
      M.G[r][c] = W[r][0]*Ppi[0][c] + W[r][1]*Ppi[1][c] + W[r][2]*Ppi[2][c] + W[r][3]*Ppi[3][c];
#pragma unroll
  for (int r = 0; r < 4; ++r)
    M.c[r] = mf[r] - (M.G[r][0]*mp[0] + M.G[r][1]*mp[1] + M.G[r][2]*mp[2] + M.G[r][3]*mp[3]);
  float V[4][4];
#pragma unroll
  for (int r = 0; r < 4; ++r)
#pragma unroll
    for (int c = 0; c < 4; ++c)
      V[r][c] = M.G[r][0]*Pp[0][c] + M.G[r][1]*Pp[1][c] + M.G[r][2]*Pp[2][c] + M.G[r][3]*Pp[3][c];
#pragma unroll
  for (int r = 0; r < 4; ++r)
#pragma unroll
    for (int c = r; c < 4; ++c) {
      float v = Pf[r][c] - (V[r][0]*M.G[c][0] + V[r][1]*M.G[c][1]
                          + V[r][2]*M.G[c][2] + V[r][3]*M.G[c][3]);
      M.Dm[r][c] = v; M.Dm[c][r] = v;
    }
}

__device__ __forceinline__ void store_map(float* __restrict__ p, const Map& M) {
  *(float4*)&p[0]  = make_float4(M.G[0][0],M.G[0][1],M.G[0][2],M.G[0][3]);
  *(float4*)&p[4]  = make_float4(M.G[1][0],M.G[1][1],M.G[1][2],M.G[1][3]);
  *(float4*)&p[8]  = make_float4(M.G[2][0],M.G[2][1],M.G[2][2],M.G[2][3]);
  *(float4*)&p[12] = make_float4(M.G[3][0],M.G[3][1],M.G[3][2],M.G[3][3]);
  *(float4*)&p[16] = make_float4(M.c[0],M.c[1],M.c[2],M.c[3]);
  *(float4*)&p[20] = make_float4(M.Dm[0][0],M.Dm[0][1],M.Dm[0][2],M.Dm[0][3]);
  *(float4*)&p[24] = make_float4(M.Dm[1][0],M.Dm[1][1],M.Dm[1][2],M.Dm[1][3]);
  *(float4*)&p[28] = make_float4(M.Dm[2][0],M.Dm[2][1],M.Dm[2][2],M.Dm[2][3]);
  *(float4*)&p[32] = make_float4(M.Dm[3][0],M.Dm[3][1],M.Dm[3][2],M.Dm[3][3]);
}
__device__ __forceinline__ void load_map(const float* __restrict__ p, Map& M) {
  float4 g0=*(const float4*)&p[0], g1=*(const float4*)&p[4],
         g2=*(const float4*)&p[8], g3=*(const float4*)&p[12];
  float4 cv=*(const float4*)&p[16];
  float4 d0=*(const float4*)&p[20], d1=*(const float4*)&p[24],
         d2=*(const float4*)&p[28], d3=*(const float4*)&p[32];
  M.G[0][0]=g0.x;M.G[0][1]=g0.y;M.G[0][2]=g0.z;M.G[0][3]=g0.w;
  M.G[1][0]=g1.x;M.G[1][1]=g1.y;M.G[1][2]=g1.z;M.G[1][3]=g1.w;
  M.G[2][0]=g2.x;M.G[2][1]=g2.y;M.G[2][2]=g2.z;M.G[2][3]=g2.w;
  M.G[3][0]=g3.x;M.G[3][1]=g3.y;M.G[3][2]=g3.z;M.G[3][3]=g3.w;
  M.c[0]=cv.x;M.c[1]=cv.y;M.c[2]=cv.z;M.c[3]=cv.w;
  M.Dm[0][0]=d0.x;M.Dm[0][1]=d0.y;M.Dm[0][2]=d0.z;M.Dm[0][3]=d0.w;
  M.Dm[1][0]=d1.x;M.Dm[1][1]=d1.y;M.Dm[1][2]=d1.z;M.Dm[1][3]=d1.w;
  M.Dm[2][0]=d2.x;M.Dm[2][1]=d2.y;M.Dm[2][2]=d2.z;M.Dm[2][3]=d2.w;
  M.Dm[3][0]=d3.x;M.Dm[3][1]=d3.y;M.Dm[3][2]=d3.z;M.Dm[3][3]=d3.w;
}

// K3 phase A: per (chunk, filter) compose chunk aggregate right-to-left
__global__ void __launch_bounds__(64, 1) k_phaseA(
    const float* __restrict__ fm, const float* __restrict__ fP,
    const float* __restrict__ Ag, const float* __restrict__ bg,
    const float* __restrict__ qp, float* __restrict__ Cw) {
  const int cc = blockIdx.x;  // chunk
  const int i  = threadIdx.x; // filter
  float A[4][4], Q[4][4], b[4];
  load_A_b_Q(Ag, bg, qp, A, b, Q);
  Map agg; map_identity(agg);
  int a = cc * CLEN;
  int bb = a + CLEN - 1; if (bb > T - 2) bb = T - 2;
  for (int t = bb; t >= a; --t) {
    Map f; make_ft(t, i, fm, fP, A, b, Q, f);
    compose(f, agg, agg);
  }
  store_map(&Cw[((size_t)i*CH + cc)*36], agg);
}

// K4 phase B: per filter, exclusive suffix scan of chunk aggregates
__global__ void __launch_bounds__(64, 1) k_phaseB(
    const float* __restrict__ Cw, float* __restrict__ Ew) {
  const int i = threadIdx.x;
  Map agg; map_identity(agg);
  for (int cc = CH - 1; cc >= 0; --cc) {
    store_map(&Ew[((size_t)i*CH + cc)*36], agg);
    Map Cc; load_map(&Cw[((size_t)i*CH + cc)*36], Cc);
    compose(Cc, agg, agg);
  }
}

// cholesky of sP+1e-5 I, z = sm + L eps, out = z @ dec_w + dec_b
__device__ __forceinline__ void recon(int t, int i,
    const float sm[4], const float sP[4][4],
    const float* __restrict__ eps, const float* __restrict__ dw,
    const float* __restrict__ db, float* __restrict__ out) {
  float a00 = sP[0][0]+1e-5f, a11 = sP[1][1]+1e-5f, a22 = sP[2][2]+1e-5f, a33 = sP[3][3]+1e-5f;
  float L00 = sqrtf(a00);
  float r0 = __fdividef(1.0f, L00);
  float L10 = sP[1][0]*r0, L20 = sP[2][0]*r0, L30 = sP[3][0]*r0;
  float L11 = sqrtf(a11 - L10*L10);
  float r1 = __fdividef(1.0f, L11);
  float L21 = (sP[2][1]-L20*L10)*r1, L31 = (sP[3][1]-L30*L10)*r1;
  float L22 = sqrtf(a22 - L20*L20 - L21*L21);
  float r2 = __fdividef(1.0f, L22);
  float L32 = (sP[3][2]-L30*L20-L31*L21)*r2;
  float L33 = sqrtf(a33 - L30*L30 - L31*L31 - L32*L32);
  float4 e = *(const float4*)&eps[((size_t)t*NB + i)*4];
  float z0 = sm[0] + L00*e.x;
  float z1 = sm[1] + L10*e.x + L11*e.y;
  float z2 = sm[2] + L20*e.x + L21*e.y + L22*e.z;
  float z3 = sm[3] + L30*e.x + L31*e.y + L32*e.z + L33*e.w;
#pragma unroll
  for (int p = 0; p < 3; ++p)
    out[((size_t)t*NB + i)*3 + p] =
        db[p] + z0*dw[0*3+p] + z1*dw[1*3+p] + z2*dw[2*3+p] + z3*dw[3*3+p];
}

// K5 phase C: apply exclusive suffix, walk chunk downward emitting sm/sP + recon
__global__ void __launch_bounds__(64, 1) k_phaseC(
    const float* __restrict__ fm, const float* __restrict__ fP,
    const float* __restrict__ Ew,
    const float* __restrict__ Ag, const float* __restrict__ bg,
    const float* __restrict__ qp,
    const float* __restrict__ eps, const float* __restrict__ dw,
    const float* __restrict__ db, float* __restrict__ out) {
  const int cc = blockIdx.x;
  const int i  = threadIdx.x;
  float A[4][4], Q[4][4], b[4];
  load_A_b_Q(Ag, bg, qp, A, b, Q);

  // final filtered state (t = T-1) == final smoothed state
  float4 mv = *(const float4*)&fm[((size_t)(T-1)*NB + i)*4];
  float mT[4] = { mv.x, mv.y, mv.z, mv.w };
  const float* fpT = &fP[((size_t)(T-1)*NB + i)*16];
  float4 p0=*(const float4*)&fpT[0], p1=*(const float4*)&fpT[4],
         p2=*(const float4*)&fpT[8], p3=*(const float4*)&fpT[12];
  float PT[4][4] = {{p0.x,p0.y,p0.z,p0.w},{p1.x,p1.y,p1.z,p1.w},
                    {p2.x,p2.y,p2.z,p2.w},{p3.x,p3.y,p3.z,p3.w}};

  Map E; load_map(&Ew[((size_t)i*CH + cc)*36], E);

  // state = E(s_final) : smoothed state at t = first index of chunk cc+1
  float sm[4], sP[4][4];
#pragma unroll
  for (int r = 0; r < 4; ++r)
    sm[r] = E.c[r] + E.G[r][0]*mT[0] + E.G[r][1]*mT[1] + E.G[r][2]*mT[2] + E.G[r][3]*mT[3];
  {
    float V[4][4];
#pragma unroll
    for (int r = 0; r < 4; ++r)
#pragma unroll
      for (int c = 0; c < 4; ++c)
        V[r][c] = E.G[r][0]*PT[0][c] + E.G[r][1]*PT[1][c] + E.G[r][2]*PT[2][c] + E.G[r][3]*PT[3][c];
#pragma unroll
    for (int r = 0; r < 4; ++r)
#pragma unroll
      for (int c = r; c < 4; ++c) {
        float v = E.Dm[r][c] + V[r][0]*E.G[c][0] + V[r][1]*E.G[c][1]
                             + V[r][2]*E.G[c][2] + V[r][3]*E.G[c][3];
        sP[r][c] = v; sP[c][r] = v;
      }
  }

  if (cc == CH - 1) recon(T - 1, i, mT, PT, eps, dw, db, out);

  int a = cc * CLEN;
  int bb = a + CLEN - 1; if (bb > T - 2) bb = T - 2;
  for (int t = bb; t >= a; --t) {
    Map f; make_ft(t, i, fm, fP, A, b, Q, f);
    float smn[4];
#pragma unroll
    for (int r = 0; r < 4; ++r)
      smn[r] = f.c[r] + f.G[r][0]*sm[0] + f.G[r][1]*sm[1] + f.G[r][2]*sm[2] + f.G[r][3]*sm[3];
    float V[4][4];
#pragma unroll
    for (int r = 0; r < 4; ++r)
#pragma unroll
      for (int c = 0; c < 4; ++c)
        V[r][c] = f.G[r][0]*sP[0][c] + f.G[r][1]*sP[1][c] + f.G[r][2]*sP[2][c] + f.G[r][3]*sP[3][c];
#pragma unroll
    for (int r = 0; r < 4; ++r)
#pragma unroll
      for (int c = r; c < 4; ++c) {
        float v = f.Dm[r][c] + V[r][0]*f.G[c][0] + V[r][1]*f.G[c][1]
                             + V[r][2]*f.G[c][2] + V[r][3]*f.G[c][3];
        sP[r][c] = v; sP[c][r] = v;
      }
    sm[0]=smn[0]; sm[1]=smn[1]; sm[2]=smn[2]; sm[3]=smn[3];
    recon(t, i, sm, sP, eps, dw, db, out);
  }
}

// ==========================================================================
extern "C" void kernel_launch(void* const* d_in, const int* in_sizes, int n_in,
                              void* d_out, int out_size, void* d_ws, size_t ws_size,
                              hipStream_t stream) {
  const float* x   = (const float*)d_in[0];
  const float* eps = (const float*)d_in[1];
  const float* w1  = (const float*)d_in[2];
  const float* b1  = (const float*)d_in[3];
  const float* wx  = (const float*)d_in[4];
  const float* bx  = (const float*)d_in[5];
  const float* wl  = (const float*)d_in[6];
  const float* bl  = (const float*)d_in[7];
  const float* dw  = (const float*)d_in[8];
  const float* db  = (const float*)d_in[9];
  const float* Ag  = (const float*)d_in[10];
  const float* bg  = (const float*)d_in[11];
  const float* qp  = (const float*)d_in[12];

  float* ws    = (float*)d_ws;
  float* xhat  = ws + OFF_XHAT;
  float* sigma = ws + OFF_SIGMA;
  float* fm    = ws + OFF_FM;
  float* fP    = ws + OFF_FP;
  float* Cw    = ws + OFF_C;
  float* Ew    = ws + OFF_E;
  float* out   = (float*)d_out;

  k_encoder<<<(TP1*NB + 255)/256, 256, 0, stream>>>(x, w1, b1, wx, bx, wl, bl, xhat, sigma);
  k_filter<<<NB, NB, 0, stream>>>(xhat, sigma, Ag, bg, qp, fm, fP);
  k_phaseA<<<CH, NB, 0, stream>>>(fm, fP, Ag, bg, qp, Cw);
  k_phaseB<<<1, NB, 0, stream>>>(Cw, Ew);
  k_phaseC<<<CH, NB, 0, stream>>>(fm, fP, Ew, Ag, bg, qp, eps, dw, db, out);
}

// Round 4
// 2525.673 us; speedup vs baseline: 1.4353x; 1.3738x over previous
//
#include <hip/hip_runtime.h>
#include <math.h>

#define D4   4
#define NB   64      // batch = #filters = #observations
#define T    2048
#define TP1  2049
#define HID  20
#define POS  3
#define CH   64      // chunks for backward parallel scan
#define CLEN 32      // chunk length (CH*CLEN >= T-1)

#define LOG_2PI 1.8378770664093453f
#define TWO_LOG_2PI 3.6757541328186906f

// ---- workspace layout (floats) -------------------------------------------
#define OFF_XHAT  0
#define OFF_SIGMA (TP1*NB*4)
#define OFF_FM    (2*TP1*NB*4)
#define OFF_FP    (OFF_FM + T*NB*4)
#define OFF_C     (OFF_FP + T*NB*16)
#define OFF_E     (OFF_C + NB*CH*36)

// ---- DPP wave reductions (VALU pipe, no LDS) ------------------------------
template<int CTRL, int RM>
__device__ __forceinline__ float dpp_sum_step(float v) {
  int t = __builtin_amdgcn_update_dpp(0, __float_as_int(v), CTRL, RM, 0xF, true);
  return v + __int_as_float(t);
}
template<int CTRL, int RM>
__device__ __forceinline__ float dpp_max_step(float v) {
  int vi = __float_as_int(v);
  int t = __builtin_amdgcn_update_dpp(vi, vi, CTRL, RM, 0xF, false);
  return fmaxf(v, __int_as_float(t));
}
// sum across 64 lanes; TOTAL lands in lane 63 (no broadcast)
__device__ __forceinline__ float wsum_v(float v) {
  v = dpp_sum_step<0x111, 0xF>(v);   // row_shr:1
  v = dpp_sum_step<0x112, 0xF>(v);   // row_shr:2
  v = dpp_sum_step<0x114, 0xF>(v);   // row_shr:4
  v = dpp_sum_step<0x118, 0xF>(v);   // row_shr:8
  v = dpp_sum_step<0x142, 0xA>(v);   // row_bcast:15 into rows 1,3
  v = dpp_sum_step<0x143, 0xC>(v);   // row_bcast:31 into rows 2,3
  return v;
}
__device__ __forceinline__ float wmax(float v) {
  v = dpp_max_step<0x111, 0xF>(v);
  v = dpp_max_step<0x112, 0xF>(v);
  v = dpp_max_step<0x114, 0xF>(v);
  v = dpp_max_step<0x118, 0xF>(v);
  v = dpp_max_step<0x142, 0xA>(v);
  v = dpp_max_step<0x143, 0xC>(v);
  return __int_as_float(__builtin_amdgcn_readlane(__float_as_int(v), 63));
}
__device__ __forceinline__ float rdlane(float v, int l) {
  return __int_as_float(__builtin_amdgcn_readlane(__float_as_int(v), l));
}

// ---- 4x4 inverse (adjugate, general); returns det ------------------------
__device__ __forceinline__ float inv4(const float a[4][4], float inv[4][4]) {
  float s0 = a[0][0]*a[1][1] - a[1][0]*a[0][1];
  float s1 = a[0][0]*a[1][2] - a[1][0]*a[0][2];
  float s2 = a[0][0]*a[1][3] - a[1][0]*a[0][3];
  float s3 = a[0][1]*a[1][2] - a[1][1]*a[0][2];
  float s4 = a[0][1]*a[1][3] - a[1][1]*a[0][3];
  float s5 = a[0][2]*a[1][3] - a[1][2]*a[0][3];
  float c5 = a[2][2]*a[3][3] - a[3][2]*a[2][3];
  float c4 = a[2][1]*a[3][3] - a[3][1]*a[2][3];
  float c3 = a[2][1]*a[3][2] - a[3][1]*a[2][2];
  float c2 = a[2][0]*a[3][3] - a[3][0]*a[2][3];
  float c1 = a[2][0]*a[3][2] - a[3][0]*a[2][2];
  float c0 = a[2][0]*a[3][1] - a[3][0]*a[2][1];
  float det = s0*c5 - s1*c4 + s2*c3 + s3*c2 - s4*c1 + s5*c0;
  float id = __fdividef(1.0f, det);
  inv[0][0] = ( a[1][1]*c5 - a[1][2]*c4 + a[1][3]*c3) * id;
  inv[0][1] = (-a[0][1]*c5 + a[0][2]*c4 - a[0][3]*c3) * id;
  inv[0][2] = ( a[3][1]*s5 - a[3][2]*s4 + a[3][3]*s3) * id;
  inv[0][3] = (-a[2][1]*s5 + a[2][2]*s4 - a[2][3]*s3) * id;
  inv[1][0] = (-a[1][0]*c5 + a[1][2]*c2 - a[1][3]*c1) * id;
  inv[1][1] = ( a[0][0]*c5 - a[0][2]*c2 + a[0][3]*c1) * id;
  inv[1][2] = (-a[3][0]*s5 + a[3][2]*s2 - a[3][3]*s1) * id;
  inv[1][3] = ( a[2][0]*s5 - a[2][2]*s2 + a[2][3]*s1) * id;
  inv[2][0] = ( a[1][0]*c4 - a[1][1]*c2 + a[1][3]*c0) * id;
  inv[2][1] = (-a[0][0]*c4 + a[0][1]*c2 - a[0][3]*c0) * id;
  inv[2][2] = ( a[3][0]*s4 - a[3][1]*s2 + a[3][3]*s0) * id;
  inv[2][3] = (-a[2][0]*s4 + a[2][1]*s2 - a[2][3]*s0) * id;
  inv[3][0] = (-a[1][0]*c3 + a[1][1]*c1 - a[1][2]*c0) * id;
  inv[3][1] = ( a[0][0]*c3 - a[0][1]*c1 + a[0][2]*c0) * id;
  inv[3][2] = (-a[3][0]*s3 + a[3][1]*s1 - a[3][2]*s0) * id;
  inv[3][3] = ( a[2][0]*s3 - a[2][1]*s1 + a[2][2]*s0) * id;
  return det;
}

// ---- Q = L L^T from q_param (tril_indices row-major order) ---------------
__device__ __forceinline__ void build_Q(const float* __restrict__ qp, float Q[4][4]) {
  float L[4][4] = {{0.f,0.f,0.f,0.f},{0.f,0.f,0.f,0.f},{0.f,0.f,0.f,0.f},{0.f,0.f,0.f,0.f}};
  L[0][0] = expf(qp[0]);
  L[1][0] = qp[1]; L[1][1] = expf(qp[2]);
  L[2][0] = qp[3]; L[2][1] = qp[4]; L[2][2] = expf(qp[5]);
  L[3][0] = qp[6]; L[3][1] = qp[7]; L[3][2] = qp[8]; L[3][3] = expf(qp[9]);
#pragma unroll
  for (int r = 0; r < 4; ++r)
#pragma unroll
    for (int c = 0; c < 4; ++c) {
      float v = 0.f;
#pragma unroll
      for (int k = 0; k < 4; ++k) v += L[r][k] * L[c][k];
      Q[r][c] = v;
    }
}

__device__ __forceinline__ void load_A_b_Q(const float* __restrict__ Ag,
                                           const float* __restrict__ bg,
                                           const float* __restrict__ qp,
                                           float A[4][4], float b[4], float Q[4][4]) {
#pragma unroll
  for (int r = 0; r < 4; ++r) {
    b[r] = bg[r];
#pragma unroll
    for (int c = 0; c < 4; ++c) A[r][c] = Ag[r * 4 + c];
  }
  build_Q(qp, Q);
}

// ==========================================================================
// K1: encoder
// ==========================================================================
__global__ void k_encoder(const float* __restrict__ x,
                          const float* __restrict__ w1, const float* __restrict__ b1,
                          const float* __restrict__ wx, const float* __restrict__ bx,
                          const float* __restrict__ wl, const float* __restrict__ bl,
                          float* __restrict__ xhat, float* __restrict__ sigma) {
  int idx = blockIdx.x * blockDim.x + threadIdx.x;
  if (idx >= TP1 * NB) return;
  float x0 = x[idx*3+0], x1 = x[idx*3+1], x2 = x[idx*3+2];
  float xh[4], lm[4];
#pragma unroll
  for (int k = 0; k < 4; ++k) { xh[k] = bx[k]; lm[k] = bl[k]; }
#pragma unroll
  for (int j = 0; j < HID; ++j) {
    float h = x0*w1[0*HID+j] + x1*w1[1*HID+j] + x2*w1[2*HID+j] + b1[j];
    h = fmaxf(h, 0.0f);
#pragma unroll
    for (int k = 0; k < 4; ++k) { xh[k] += h * wx[j*4+k]; lm[k] += h * wl[j*4+k]; }
  }
  *(float4*)&xhat[(size_t)idx*4]  = make_float4(xh[0], xh[1], xh[2], xh[3]);
  *(float4*)&sigma[(size_t)idx*4] = make_float4(expf(0.5f*lm[0]), expf(0.5f*lm[1]),
                                                expf(0.5f*lm[2]), expf(0.5f*lm[3]));
}

// ==========================================================================
// K2: forward mixture Kalman filter — 2 waves per filter (128-thread block)
//   wave 0 owns chains {W, wm0..3, q00,q01,q02}; wave 1 owns {q03,q11..q33}
//   per-step exchange of 15 sums via double-buffered LDS + 1 barrier
//   predict distributed: lane e owns one Pp/mp entry (14 fma + 14 readlane)
// ==========================================================================
__global__ void __launch_bounds__(128, 1) k_filter(
    const float* __restrict__ xhat, const float* __restrict__ sigma,
    const float* __restrict__ Ag, const float* __restrict__ bg,
    const float* __restrict__ qp,
    float* __restrict__ fm, float* __restrict__ fP) {
  const int fi  = blockIdx.x;        // filter
  const int tid = threadIdx.x;
  const int wv  = tid >> 6;          // wave id (0/1)
  const int n   = tid & 63;          // observation lane

  __shared__ __align__(16) float xch[2][16];

  // ---- per-lane predict-entry setup (once) ----
  // lanes 0..9: upper-triangular Pp entry e -> (r,c)
  // lanes 10..13: mp row r = n-10
  int r, c;
  if (n < 10) {
    r = (n < 4) ? 0 : (n < 7) ? 1 : (n < 9) ? 2 : 3;
    c = (n < 4) ? n : (n < 7) ? n - 3 : (n < 9) ? n - 5 : 3;
  } else if (n < 14) { r = n - 10; c = 0; }
  else { r = 0; c = 0; }

  float ar0 = Ag[r*4+0], ar1 = Ag[r*4+1], ar2 = Ag[r*4+2], ar3 = Ag[r*4+3];
  float ac0 = Ag[c*4+0], ac1 = Ag[c*4+1], ac2 = Ag[c*4+2], ac3 = Ag[c*4+3];
  float qmask = (n < 10) ? 1.0f : 0.0f;
  float pmask = (n >= 10 && n < 14) ? 1.0f : 0.0f;
  // slot j -> (u,v): 0:(0,0) 1:(0,1) 2:(0,2) 3:(0,3) 4:(1,1) 5:(1,2) 6:(1,3) 7:(2,2) 8:(2,3) 9:(3,3)
  float wp0 = (ar0*ac0) * qmask;
  float wp1 = (ar0*ac1 + ar1*ac0) * qmask;
  float wp2 = (ar0*ac2 + ar2*ac0) * qmask;
  float wp3 = (ar0*ac3 + ar3*ac0) * qmask;
  float wp4 = (ar1*ac1) * qmask;
  float wp5 = (ar1*ac2 + ar2*ac1) * qmask;
  float wp6 = (ar1*ac3 + ar3*ac1) * qmask;
  float wp7 = (ar2*ac2) * qmask;
  float wp8 = (ar2*ac3 + ar3*ac2) * qmask;
  float wp9 = (ar3*ac3) * qmask;
  float wm0_ = ar0 * pmask, wm1_ = ar1 * pmask, wm2_ = ar2 * pmask, wm3_ = ar3 * pmask;

  // init term: lane<10 -> Q_e ; lane 10..13 -> b_r ; else 0
  float initv;
  {
    int trir = r*(r+1)/2, tric = c*(c+1)/2;
    float Lr[4], Lc[4];
#pragma unroll
    for (int k = 0; k < 4; ++k) {
      Lr[k] = (k > r) ? 0.0f : (k == r ? expf(qp[trir+r]) : qp[trir+k]);
      Lc[k] = (k > c) ? 0.0f : (k == c ? expf(qp[tric+c]) : qp[tric+k]);
    }
    float Qe = Lr[0]*Lc[0] + Lr[1]*Lc[1] + Lr[2]*Lc[2] + Lr[3]*Lc[3];
    if (n < 10)      initv = Qe;
    else if (n < 14) initv = bg[n-10];
    else             initv = 0.0f;
  }

  // ---- uniform state: m, upper-tri P (slot layout as above) ----
  float mv0, mv1, mv2, mv3;
  float Pu0, Pu1, Pu2, Pu3, Pu4, Pu5, Pu6, Pu7, Pu8, Pu9;
  {
    float4 m0 = *(const float4*)&xhat[fi*4];
    float4 s0 = *(const float4*)&sigma[fi*4];
    mv0 = m0.x; mv1 = m0.y; mv2 = m0.z; mv3 = m0.w;
    Pu0 = s0.x; Pu4 = s0.y; Pu7 = s0.z; Pu9 = s0.w;
    Pu1 = Pu2 = Pu3 = Pu5 = Pu6 = Pu8 = 0.0f;
  }

  // preload obs row 1 (step t uses row t+1)
  float4 zz  = *(const float4*)&xhat[(size_t)(NB + n)*4];
  float4 sgc = *(const float4*)&sigma[(size_t)(NB + n)*4];

  for (int t = 0; t < T; ++t) {
    int nr = (t + 2 <= TP1 - 1) ? (t + 2) : (TP1 - 1);
    float4 zn  = *(const float4*)&xhat[((size_t)nr*NB + n)*4];
    float4 sgn = *(const float4*)&sigma[((size_t)nr*NB + n)*4];

    // ---- distributed predict: lane e computes its Pp/mp entry ----
    float a0 = initv;
    a0 = fmaf(wp0, Pu0, a0);
    a0 = fmaf(wp1, Pu1, a0);
    a0 = fmaf(wp2, Pu2, a0);
    a0 = fmaf(wp3, Pu3, a0);
    a0 = fmaf(wp4, Pu4, a0);
    float a1 = wp5 * Pu5;
    a1 = fmaf(wp6, Pu6, a1);
    a1 = fmaf(wp7, Pu7, a1);
    a1 = fmaf(wp8, Pu8, a1);
    a1 = fmaf(wp9, Pu9, a1);
    a0 = fmaf(wm0_, mv0, a0);
    a0 = fmaf(wm1_, mv1, a0);
    a0 = fmaf(wm2_, mv2, a0);
    a0 = fmaf(wm3_, mv3, a0);
    float pe = a0 + a1;
    // broadcast entries (wave-uniform scalars)
    float p00 = rdlane(pe, 0), p01 = rdlane(pe, 1), p02 = rdlane(pe, 2), p03 = rdlane(pe, 3);
    float p11 = rdlane(pe, 4), p12 = rdlane(pe, 5), p13 = rdlane(pe, 6);
    float p22 = rdlane(pe, 7), p23 = rdlane(pe, 8), p33 = rdlane(pe, 9);
    float mp0 = rdlane(pe,10), mp1 = rdlane(pe,11), mp2 = rdlane(pe,12), mp3 = rdlane(pe,13);

    // ---- per-lane: S = Pp + diag(sigma); symmetric adjugate inverse ----
    float s00 = p00 + sgc.x, s11 = p11 + sgc.y, s22 = p22 + sgc.z, s33 = p33 + sgc.w;
    float s01 = p01, s02 = p02, s03 = p03, s12 = p12, s13 = p13, s23 = p23;

    float m0_ = s00*s11 - s01*s01;
    float m1_ = s00*s12 - s01*s02;
    float m2_ = s00*s13 - s01*s03;
    float m3_ = s01*s12 - s11*s02;
    float m4_ = s01*s13 - s11*s03;
    float m5_ = s02*s13 - s12*s03;
    float n5_ = s22*s33 - s23*s23;
    float n4_ = s12*s33 - s13*s23;
    float n3_ = s12*s23 - s13*s22;
    float n2_ = s02*s33 - s03*s23;
    float n1_ = s02*s23 - s03*s22;
    float det = m0_*n5_ - m1_*n4_ + m2_*n3_ + m3_*n2_ - m4_*n1_ + m5_*m5_;
    float id  = __fdividef(1.0f, det);
    float i00 = ( s11*n5_ - s12*n4_ + s13*n3_) * id;
    float i01 = (-s01*n5_ + s02*n4_ - s03*n3_) * id;
    float i02 = ( s13*m5_ - s23*m4_ + s33*m3_) * id;
    float i03 = (-s12*m5_ + s22*m4_ - s23*m3_) * id;
    float i11 = ( s00*n5_ - s02*n2_ + s03*n1_) * id;
    float i12 = (-s03*m5_ + s23*m2_ - s33*m1_) * id;
    float i13 = ( s02*m5_ - s22*m2_ + s23*m1_) * id;
    float i22 = ( s03*m4_ - s13*m2_ + s33*m0_) * id;
    float i23 = (-s02*m4_ + s12*m2_ - s23*m0_) * id;
    float i33 = ( s02*m3_ - s12*m1_ + s22*m0_) * id;
    float logdet = __logf(det);

    float iv0 = zz.x - mp0, iv1 = zz.y - mp1, iv2 = zz.z - mp2, iv3 = zz.w - mp3;
    float y0 = i00*iv0 + i01*iv1 + i02*iv2 + i03*iv3;
    float y1 = i01*iv0 + i11*iv1 + i12*iv2 + i13*iv3;
    float y2 = i02*iv0 + i12*iv1 + i22*iv2 + i23*iv3;
    float y3 = i03*iv0 + i13*iv1 + i23*iv2 + i33*iv3;
    float quad = iv0*y0 + iv1*y1 + iv2*y2 + iv3*y3;
    float ll = -0.5f*(quad + logdet) - TWO_LOG_2PI;

    float M = wmax(ll);
    float wi = __expf(ll - M);

    // mi = mp + Pp*y  (Pp entries are uniform scalars)
    float mi0 = mp0 + p00*y0 + p01*y1 + p02*y2 + p03*y3;
    float mi1 = mp1 + p01*y0 + p11*y1 + p12*y2 + p13*y3;
    float mi2 = mp2 + p02*y0 + p12*y1 + p22*y2 + p23*y3;
    float mi3 = mp3 + p03*y0 + p13*y1 + p23*y2 + p33*y3;

    const float sd0 = sgc.x, sd1 = sgc.y, sd2 = sgc.z, sd3 = sgc.w;
    const int par = t & 1;

    if (wv == 0) {
      // X entries for owned chains
      float X00 = (p00*i00 + p01*i01 + p02*i02 + p03*i03)*sd0 + mi0*mi0;
      float X01 = (p00*i01 + p01*i11 + p02*i12 + p03*i13)*sd1 + mi0*mi1;
      float X02 = (p00*i02 + p01*i12 + p02*i22 + p03*i23)*sd2 + mi0*mi2;
      float cW  = wsum_v(wi);
      float cm0 = wsum_v(wi*mi0);
      float cm1 = wsum_v(wi*mi1);
      float cm2 = wsum_v(wi*mi2);
      float cm3 = wsum_v(wi*mi3);
      float c00 = wsum_v(wi*X00);
      float c01 = wsum_v(wi*X01);
      float c02 = wsum_v(wi*X02);
      if (n == 63) {
        float* lb = xch[par];
        lb[0] = cW;  lb[1] = cm0; lb[2] = cm1; lb[3] = cm2;
        lb[4] = cm3; lb[5] = c00; lb[6] = c01; lb[7] = c02;
      }
    } else {
      float X03 = (p00*i03 + p01*i13 + p02*i23 + p03*i33)*sd3 + mi0*mi3;
      float X11 = (p01*i01 + p11*i11 + p12*i12 + p13*i13)*sd1 + mi1*mi1;
      float X12 = (p01*i02 + p11*i12 + p12*i22 + p13*i23)*sd2 + mi1*mi2;
      float X13 = (p01*i03 + p11*i13 + p12*i23 + p13*i33)*sd3 + mi1*mi3;
      float X22 = (p02*i02 + p12*i12 + p22*i22 + p23*i23)*sd2 + mi2*mi2;
      float X23 = (p02*i03 + p12*i13 + p22*i23 + p23*i33)*sd3 + mi2*mi3;
      float X33 = (p03*i03 + p13*i13 + p23*i23 + p33*i33)*sd3 + mi3*mi3;
      float c03 = wsum_v(wi*X03);
      float c11 = wsum_v(wi*X11);
      float c12 = wsum_v(wi*X12);
      float c13 = wsum_v(wi*X13);
      float c22 = wsum_v(wi*X22);
      float c23 = wsum_v(wi*X23);
      float c33 = wsum_v(wi*X33);
      if (n == 63) {
        float* lb = xch[par];
        lb[8] = c03; lb[9] = c11; lb[10] = c12; lb[11] = c13;
        lb[12] = c22; lb[13] = c23; lb[14] = c33;
      }
    }

    __syncthreads();

    float4 A0 = *(const float4*)&xch[par][0];
    float4 A1 = *(const float4*)&xch[par][4];
    float4 A2 = *(const float4*)&xch[par][8];
    float4 A3 = *(const float4*)&xch[par][12];
    // A0 = {W, wm0, wm1, wm2}; A1 = {wm3, q00, q01, q02};
    // A2 = {q03, q11, q12, q13}; A3 = {q22, q23, q33, -}
    float rW  = __fdividef(1.0f, A0.x);
    float mu0 = A0.y*rW, mu1 = A0.z*rW, mu2 = A0.w*rW, mu3 = A1.x*rW;
    Pu0 = A1.y*rW - mu0*mu0;
    Pu1 = A1.z*rW - mu0*mu1;
    Pu2 = A1.w*rW - mu0*mu2;
    Pu3 = A2.x*rW - mu0*mu3;
    Pu4 = A2.y*rW - mu1*mu1;
    Pu5 = A2.z*rW - mu1*mu2;
    Pu6 = A2.w*rW - mu1*mu3;
    Pu7 = A3.x*rW - mu2*mu2;
    Pu8 = A3.y*rW - mu2*mu3;
    Pu9 = A3.z*rW - mu3*mu3;
    mv0 = mu0; mv1 = mu1; mv2 = mu2; mv3 = mu3;

    if (wv == 0 && n == 0) {
      *(float4*)&fm[((size_t)t*NB + fi)*4] = make_float4(mv0, mv1, mv2, mv3);
      float* fp = &fP[((size_t)t*NB + fi)*16];
      *(float4*)&fp[0]  = make_float4(Pu0, Pu1, Pu2, Pu3);
      *(float4*)&fp[4]  = make_float4(Pu1, Pu4, Pu5, Pu6);
      *(float4*)&fp[8]  = make_float4(Pu2, Pu5, Pu7, Pu8);
      *(float4*)&fp[12] = make_float4(Pu3, Pu6, Pu8, Pu9);
    }
    zz = zn; sgc = sgn;
  }
}

// ==========================================================================
// Backward smoother as an affine suffix scan (unchanged from round 2)
// ==========================================================================
struct Map { float G[4][4]; float c[4]; float Dm[4][4]; };

__device__ __forceinline__ void map_identity(Map& M) {
#pragma unroll
  for (int r = 0; r < 4; ++r) {
    M.c[r] = 0.f;
#pragma unroll
    for (int cc = 0; cc < 4; ++cc) { M.G[r][cc] = (r==cc)?1.f:0.f; M.Dm[r][cc] = 0.f; }
  }
}

__device__ __forceinline__ void compose(const Map& F, const Map& Sm, Map& R) {
  float G[4][4], cv[4], V[4][4], Dn[4][4];
#pragma unroll
  for (int r = 0; r < 4; ++r)
#pragma unroll
    for (int c = 0; c < 4; ++c)
      G[r][c] = F.G[r][0]*Sm.G[0][c] + F.G[r][1]*Sm.G[1][c]
              + F.G[r][2]*Sm.G[2][c] + F.G[r][3]*Sm.G[3][c];
#pragma unroll
  for (int r = 0; r < 4; ++r)
    cv[r] = F.c[r] + F.G[r][0]*Sm.c[0] + F.G[r][1]*Sm.c[1]
                   + F.G[r][2]*Sm.c[2] + F.G[r][3]*Sm.c[3];
#pragma unroll
  for (int r = 0; r < 4; ++r)
#pragma unroll
    for (int c = 0; c < 4; ++c)
      V[r][c] = F.G[r][0]*Sm.Dm[0][c] + F.G[r][1]*Sm.Dm[1][c]
              + F.G[r][2]*Sm.Dm[2][c] + F.G[r][3]*Sm.Dm[3][c];
#pragma unroll
  for (int r = 0; r < 4; ++r)
#pragma unroll
    for (int c = r; c < 4; ++c) {
      float v = F.Dm[r][c] + V[r][0]*F.G[c][0] + V[r][1]*F.G[c][1]
                           + V[r][2]*F.G[c][2] + V[r][3]*F.G[c][3];
      Dn[r][c] = v; Dn[c][r] = v;
    }
#pragma unroll
  for (int r = 0; r < 4; ++r) {
    R.c[r] = cv[r];
#pragma unroll
    for (int c = 0; c < 4; ++c) { R.G[r][c] = G[r][c]; R.Dm[r][c] = Dn[r][c]; }
  }
}

__device__ __forceinline__ void make_ft(int t, int i,
    const float* __restrict__ fm, const float* __restrict__ fP,
    const float A[4][4], const float b[4], const float Q[4][4], Map& M) {
  float4 mv = *(const float4*)&fm[((size_t)t*NB + i)*4];
  float mf[4] = { mv.x, mv.y, mv.z, mv.w };
  const float* fp = &fP[((size_t)t*NB + i)*16];
  float4 p0 = *(const float4*)&fp[0];
  float4 p1 = *(const float4*)&fp[4];
  float4 p2 = *(const float4*)&fp[8];
  float4 p3 = *(const float4*)&fp[12];
  float Pf[4][4] = {{p0.x,p0.y,p0.z,p0.w},{p1.x,p1.y,p1.z,p1.w},
                    {p2.x,p2.y,p2.z,p2.w},{p3.x,p3.y,p3.z,p3.w}};
  float mp[4];
#pragma unroll
  for (int r = 0; r < 4; ++r)
    mp[r] = b[r] + A[r][0]*mf[0] + A[r][1]*mf[1] + A[r][2]*mf[2] + A[r][3]*mf[3];
  float AP[4][4];
#pragma unroll
  for (int r = 0; r < 4; ++r)
#pragma unroll
    for (int c = 0; c < 4; ++c)
      AP[r][c] = A[r][0]*Pf[0][c] + A[r][1]*Pf[1][c] + A[r][2]*Pf[2][c] + A[r][3]*Pf[3][c];
  float Pp[4][4];
#pragma unroll
  for (int r = 0; r < 4; ++r)
#pragma unroll
    for (int c = r; c < 4; ++c) {
      float v = Q[r][c] + AP[r][0]*A[c][0] + AP[r][1]*A[c][1]
                        + AP[r][2]*A[c][2] + AP[r][3]*A[c][3];
      Pp[r][c] = v; Pp[c][r] = v;
    }
  float Ppi[4][4];
  inv4(Pp, Ppi);
  float W[4][4]; // Pf A^T
#pragma unroll
  for (int r = 0; r < 4; ++r)
#pragma unroll
    for (int c = 0; c < 4; ++c)
      W[r][c] = Pf[r][0]*A[c][0] + Pf[r][1]*A[c][1] + Pf[r][2]*A[c][2] + Pf[r][3]*A[c][3];
#pragma unroll
  for (int r = 0; r < 4; ++r)
#pragma unroll
    for (int c = 0; c < 4; ++c)
      M.G[r][c] = W[r][0]*Ppi[0][c] + W[r][1]*Ppi[1][c] + W[r][2]*Ppi[2][c] + W[r][3]*Ppi[3][c];
#pragma unroll
  for (int r = 0; r < 4; ++r)
    M.c[r] = mf[r] - (M.G[r][0]*mp[0] + M.G[r][1]*mp[1] + M.G[r][2]*mp[2] + M.G[r][3]*mp[3]);
  float V[4][4];
#pragma unroll
  for (int r = 0; r < 4; ++r)
#pragma unroll
    for (int c = 0; c < 4; ++c)
      V[r][c] = M.G[r][0]*Pp[0][c] + M.G[r][1]*Pp[1][c] + M.G[r][2]*Pp[2][c] + M.G[r][3]*Pp[3][c];
#pragma unroll
  for (int r = 0; r < 4; ++r)
#pragma unroll
    for (int c = r; c < 4; ++c) {
      float v = Pf[r][c] - (V[r][0]*M.G[c][0] + V[r][1]*M.G[c][1]
                          + V[r][2]*M.G[c][2] + V[r][3]*M.G[c][3]);
      M.Dm[r][c] = v; M.Dm[c][r] = v;
    }
}

__device__ __forceinline__ void store_map(float* __restrict__ p, const Map& M) {
  *(float4*)&p[0]  = make_float4(M.G[0][0],M.G[0][1],M.G[0][2],M.G[0][3]);
  *(float4*)&p[4]  = make_float4(M.G[1][0],M.G[1][1],M.G[1][2],M.G[1][3]);
  *(float4*)&p[8]  = make_float4(M.G[2][0],M.G[2][1],M.G[2][2],M.G[2][3]);
  *(float4*)&p[12] = make_float4(M.G[3][0],M.G[3][1],M.G[3][2],M.G[3][3]);
  *(float4*)&p[16] = make_float4(M.c[0],M.c[1],M.c[2],M.c[3]);
  *(float4*)&p[20] = make_float4(M.Dm[0][0],M.Dm[0][1],M.Dm[0][2],M.Dm[0][3]);
  *(float4*)&p[24] = make_float4(M.Dm[1][0],M.Dm[1][1],M.Dm[1][2],M.Dm[1][3]);
  *(float4*)&p[28] = make_float4(M.Dm[2][0],M.Dm[2][1],M.Dm[2][2],M.Dm[2][3]);
  *(float4*)&p[32] = make_float4(M.Dm[3][0],M.Dm[3][1],M.Dm[3][2],M.Dm[3][3]);
}
__device__ __forceinline__ void load_map(const float* __restrict__ p, Map& M) {
  float4 g0=*(const float4*)&p[0], g1=*(const float4*)&p[4],
         g2=*(const float4*)&p[8], g3=*(const float4*)&p[12];
  float4 cv=*(const float4*)&p[16];
  float4 d0=*(const float4*)&p[20], d1=*(const float4*)&p[24],
         d2=*(const float4*)&p[28], d3=*(const float4*)&p[32];
  M.G[0][0]=g0.x;M.G[0][1]=g0.y;M.G[0][2]=g0.z;M.G[0][3]=g0.w;
  M.G[1][0]=g1.x;M.G[1][1]=g1.y;M.G[1][2]=g1.z;M.G[1][3]=g1.w;
  M.G[2][0]=g2.x;M.G[2][1]=g2.y;M.G[2][2]=g2.z;M.G[2][3]=g2.w;
  M.G[3][0]=g3.x;M.G[3][1]=g3.y;M.G[3][2]=g3.z;M.G[3][3]=g3.w;
  M.c[0]=cv.x;M.c[1]=cv.y;M.c[2]=cv.z;M.c[3]=cv.w;
  M.Dm[0][0]=d0.x;M.Dm[0][1]=d0.y;M.Dm[0][2]=d0.z;M.Dm[0][3]=d0.w;
  M.Dm[1][0]=d1.x;M.Dm[1][1]=d1.y;M.Dm[1][2]=d1.z;M.Dm[1][3]=d1.w;
  M.Dm[2][0]=d2.x;M.Dm[2][1]=d2.y;M.Dm[2][2]=d2.z;M.Dm[2][3]=d2.w;
  M.Dm[3][0]=d3.x;M.Dm[3][1]=d3.y;M.Dm[3][2]=d3.z;M.Dm[3][3]=d3.w;
}

__global__ void __launch_bounds__(64, 1) k_phaseA(
    const float* __restrict__ fm, const float* __restrict__ fP,
    const float* __restrict__ Ag, const float* __restrict__ bg,
    const float* __restrict__ qp, float* __restrict__ Cw) {
  const int cc = blockIdx.x;
  const int i  = threadIdx.x;
  float A[4][4], Q[4][4], b[4];
  load_A_b_Q(Ag, bg, qp, A, b, Q);
  Map agg; map_identity(agg);
  int a = cc * CLEN;
  int bb = a + CLEN - 1; if (bb > T - 2) bb = T - 2;
  for (int t = bb; t >= a; --t) {
    Map f; make_ft(t, i, fm, fP, A, b, Q, f);
    compose(f, agg, agg);
  }
  store_map(&Cw[((size_t)i*CH + cc)*36], agg);
}

__global__ void __launch_bounds__(64, 1) k_phaseB(
    const float* __restrict__ Cw, float* __restrict__ Ew) {
  const int i = threadIdx.x;
  Map agg; map_identity(agg);
  for (int cc = CH - 1; cc >= 0; --cc) {
    store_map(&Ew[((size_t)i*CH + cc)*36], agg);
    Map Cc; load_map(&Cw[((size_t)i*CH + cc)*36], Cc);
    compose(Cc, agg, agg);
  }
}

__device__ __forceinline__ void recon(int t, int i,
    const float sm[4], const float sP[4][4],
    const float* __restrict__ eps, const float* __restrict__ dw,
    const float* __restrict__ db, float* __restrict__ out) {
  float a00 = sP[0][0]+1e-5f, a11 = sP[1][1]+1e-5f, a22 = sP[2][2]+1e-5f, a33 = sP[3][3]+1e-5f;
  float L00 = sqrtf(a00);
  float r0 = __fdividef(1.0f, L00);
  float L10 = sP[1][0]*r0, L20 = sP[2][0]*r0, L30 = sP[3][0]*r0;
  float L11 = sqrtf(a11 - L10*L10);
  float r1 = __fdividef(1.0f, L11);
  float L21 = (sP[2][1]-L20*L10)*r1, L31 = (sP[3][1]-L30*L10)*r1;
  float L22 = sqrtf(a22 - L20*L20 - L21*L21);
  float r2 = __fdividef(1.0f, L22);
  float L32 = (sP[3][2]-L30*L20-L31*L21)*r2;
  float L33 = sqrtf(a33 - L30*L30 - L31*L31 - L32*L32);
  float4 e = *(const float4*)&eps[((size_t)t*NB + i)*4];
  float z0 = sm[0] + L00*e.x;
  float z1 = sm[1] + L10*e.x + L11*e.y;
  float z2 = sm[2] + L20*e.x + L21*e.y + L22*e.z;
  float z3 = sm[3] + L30*e.x + L31*e.y + L32*e.z + L33*e.w;
#pragma unroll
  for (int p = 0; p < 3; ++p)
    out[((size_t)t*NB + i)*3 + p] =
        db[p] + z0*dw[0*3+p] + z1*dw[1*3+p] + z2*dw[2*3+p] + z3*dw[3*3+p];
}

__global__ void __launch_bounds__(64, 1) k_phaseC(
    const float* __restrict__ fm, const float* __restrict__ fP,
    const float* __restrict__ Ew,
    const float* __restrict__ Ag, const float* __restrict__ bg,
    const float* __restrict__ qp,
    const float* __restrict__ eps, const float* __restrict__ dw,
    const float* __restrict__ db, float* __restrict__ out) {
  const int cc = blockIdx.x;
  const int i  = threadIdx.x;
  float A[4][4], Q[4][4], b[4];
  load_A_b_Q(Ag, bg, qp, A, b, Q);

  float4 mv = *(const float4*)&fm[((size_t)(T-1)*NB + i)*4];
  float mT[4] = { mv.x, mv.y, mv.z, mv.w };
  const float* fpT = &fP[((size_t)(T-1)*NB + i)*16];
  float4 p0=*(const float4*)&fpT[0], p1=*(const float4*)&fpT[4],
         p2=*(const float4*)&fpT[8], p3=*(const float4*)&fpT[12];
  float PT[4][4] = {{p0.x,p0.y,p0.z,p0.w},{p1.x,p1.y,p1.z,p1.w},
                    {p2.x,p2.y,p2.z,p2.w},{p3.x,p3.y,p3.z,p3.w}};

  Map E; load_map(&Ew[((size_t)i*CH + cc)*36], E);

  float sm[4], sP[4][4];
#pragma unroll
  for (int r = 0; r < 4; ++r)
    sm[r] = E.c[r] + E.G[r][0]*mT[0] + E.G[r][1]*mT[1] + E.G[r][2]*mT[2] + E.G[r][3]*mT[3];
  {
    float V[4][4];
#pragma unroll
    for (int r = 0; r < 4; ++r)
#pragma unroll
      for (int c = 0; c < 4; ++c)
        V[r][c] = E.G[r][0]*PT[0][c] + E.G[r][1]*PT[1][c] + E.G[r][2]*PT[2][c] + E.G[r][3]*PT[3][c];
#pragma unroll
    for (int r = 0; r < 4; ++r)
#pragma unroll
      for (int c = r; c < 4; ++c) {
        float v = E.Dm[r][c] + V[r][0]*E.G[c][0] + V[r][1]*E.G[c][1]
                             + V[r][2]*E.G[c][2] + V[r][3]*E.G[c][3];
        sP[r][c] = v; sP[c][r] = v;
      }
  }

  if (cc == CH - 1) recon(T - 1, i, mT, PT, eps, dw, db, out);

  int a = cc * CLEN;
  int bb = a + CLEN - 1; if (bb > T - 2) bb = T - 2;
  for (int t = bb; t >= a; --t) {
    Map f; make_ft(t, i, fm, fP, A, b, Q, f);
    float smn[4];
#pragma unroll
    for (int r = 0; r < 4; ++r)
      smn[r] = f.c[r] + f.G[r][0]*sm[0] + f.G[r][1]*sm[1] + f.G[r][2]*sm[2] + f.G[r][3]*sm[3];
    float V[4][4];
#pragma unroll
    for (int r = 0; r < 4; ++r)
#pragma unroll
      for (int c = 0; c < 4; ++c)
        V[r][c] = f.G[r][0]*sP[0][c] + f.G[r][1]*sP[1][c] + f.G[r][2]*sP[2][c] + f.G[r][3]*sP[3][c];
#pragma unroll
    for (int r = 0; r < 4; ++r)
#pragma unroll
      for (int c = r; c < 4; ++c) {
        float v = f.Dm[r][c] + V[r][0]*f.G[c][0] + V[r][1]*f.G[c][1]
                             + V[r][2]*f.G[c][2] + V[r][3]*f.G[c][3];
        sP[r][c] = v; sP[c][r] = v;
      }
    sm[0]=smn[0]; sm[1]=smn[1]; sm[2]=smn[2]; sm[3]=smn[3];
    recon(t, i, sm, sP, eps, dw, db, out);
  }
}

// ==========================================================================
extern "C" void kernel_launch(void* const* d_in, const int* in_sizes, int n_in,
                              void* d_out, int out_size, void* d_ws, size_t ws_size,
                              hipStream_t stream) {
  const float* x   = (const float*)d_in[0];
  const float* eps = (const float*)d_in[1];
  const float* w1  = (const float*)d_in[2];
  const float* b1  = (const float*)d_in[3];
  const float* wx  = (const float*)d_in[4];
  const float* bx  = (const float*)d_in[5];
  const float* wl  = (const float*)d_in[6];
  const float* bl  = (const float*)d_in[7];
  const float* dw  = (const float*)d_in[8];
  const float* db  = (const float*)d_in[9];
  const float* Ag  = (const float*)d_in[10];
  const float* bg  = (const float*)d_in[11];
  const float* qp  = (const float*)d_in[12];

  float* ws    = (float*)d_ws;
  float* xhat  = ws + OFF_XHAT;
  float* sigma = ws + OFF_SIGMA;
  float* fm    = ws + OFF_FM;
  float* fP    = ws + OFF_FP;
  float* Cw    = ws + OFF_C;
  float* Ew    = ws + OFF_E;
  float* out   = (float*)d_out;

  k_encoder<<<(TP1*NB + 255)/256, 256, 0, stream>>>(x, w1, b1, wx, bx, wl, bl, xhat, sigma);
  k_filter<<<NB, 128, 0, stream>>>(xhat, sigma, Ag, bg, qp, fm, fP);
  k_phaseA<<<CH, NB, 0, stream>>>(fm, fP, Ag, bg, qp, Cw);
  k_phaseB<<<1, NB, 0, stream>>>(Cw, Ew);
  k_phaseC<<<CH, NB, 0, stream>>>(fm, fP, Ew, Ag, bg, qp, eps, dw, db, out);
}